// Round 2
// baseline (962.772 us; speedup 1.0000x reference)
//
#include <hip/hip_runtime.h>
#include <hip/hip_bf16.h>
#include <cstdint>
#include <cstddef>

typedef __hip_bfloat16 bf16;
using short8 = __attribute__((ext_vector_type(8))) short;
using f32x4  = __attribute__((ext_vector_type(4))) float;

__device__ __forceinline__ float s2f(short s) {
  unsigned u = ((unsigned)(unsigned short)s) << 16;
  return __builtin_bit_cast(float, u);
}
__device__ __forceinline__ short f2s(float f) {  // RNE f32->bf16
  unsigned u = __builtin_bit_cast(unsigned, f);
  u += 0x7fffu + ((u >> 16) & 1u);
  return (short)(u >> 16);
}

// ---------------- 1x1 conv + PReLU into zero-padded (+1 ring) f32 output ------------
__global__ __launch_bounds__(256) void k_conv1x1(
    const float* __restrict__ in, const float* __restrict__ w,
    const float* __restrict__ bias, const float* __restrict__ aprm,
    float* __restrict__ out, int Cout, int Hin, int Win, int total)
{
  int idx = blockIdx.x * 256 + threadIdx.x;
  if (idx >= total) return;
  int Wp = Win + 2, Hp = Hin + 2;
  int x = idx % Wp;
  int t = idx / Wp;
  int y = t % Hp; t /= Hp;
  int o = t % Cout; int n = t / Cout;
  if (x == 0 || x == Wp - 1 || y == 0 || y == Hp - 1) { out[idx] = 0.0f; return; }
  int cs = Hin * Win;
  const float* ip = in + (size_t)n * 64 * cs + (size_t)(y - 1) * Win + (x - 1);
  const float* wp = w + o * 64;
  float s = bias[o];
#pragma unroll 16
  for (int ci = 0; ci < 64; ci++)
    s += wp[ci] * ip[(size_t)ci * cs];
  float a = aprm[0];
  out[idx] = s >= 0.0f ? s : a * s;
}

// ---------------- key patches, L2-normalized, softmax scale 10 folded in ------------
// one wave per (n,l); Kp[n][l][k] = REFpad patch elem * 10/(||patch||+1e-4), bf16
__global__ __launch_bounds__(256) void k_kp(const float* __restrict__ refpad, bf16* __restrict__ Kp)
{
  int wid = blockIdx.x * 4 + (threadIdx.x >> 6);
  int lane = threadIdx.x & 63;
  if (wid >= 4 * 2304) return;
  int n = wid / 2304, l = wid % 2304, lh = l / 48, lw = l % 48;
  float v[5]; float ss = 0.f;
#pragma unroll
  for (int i = 0; i < 5; i++) {
    int k = lane + 64 * i; v[i] = 0.f;
    if (k < 288) {
      int c = k / 9, rr = (k % 9) / 3, sc = k % 3;
      v[i] = refpad[((size_t)(n * 32 + c) * 50 + lh + rr) * 50 + lw + sc];
      ss += v[i] * v[i];
    }
  }
#pragma unroll
  for (int off = 32; off; off >>= 1) ss += __shfl_xor(ss, off);
  float inv = 10.f / (sqrtf(ss) + 1e-4f);
#pragma unroll
  for (int i = 0; i < 5; i++) {
    int k = lane + 64 * i;
    if (k < 288) Kp[(size_t)wid * 288 + k] = __float2bfloat16(v[i] * inv);
  }
}

// ---------------- query patches Xp[n][p][288], bf16 ----------------
__global__ __launch_bounds__(256) void k_xp(const float* __restrict__ mbpad, bf16* __restrict__ Xp, int total)
{
  int idx = blockIdx.x * 256 + threadIdx.x;
  if (idx >= total) return;
  int k = idx % 288; int p = (idx / 288) % 9216; int n = idx / (288 * 9216);
  int c = k / 9, rr = (k % 9) / 3, sc = k % 3;
  int ph = p / 96, pw = p % 96;
  Xp[idx] = __float2bfloat16(mbpad[((size_t)(n * 32 + c) * 98 + ph + rr) * 98 + pw + sc]);
}

// ---------------- shifted value matrix Abase[n][d][o][l] = base[o, l - delta(d)] ----
__global__ __launch_bounds__(256) void k_abase(const float* __restrict__ basepad, bf16* __restrict__ Ab, int total)
{
  int idx = blockIdx.x * 256 + threadIdx.x;
  if (idx >= total) return;
  int l = idx % 2304; int o = (idx / 2304) % 64; int d = (idx / (2304 * 64)) % 9; int n = idx / (2304 * 576);
  int di = d / 3 - 1, dj = d % 3 - 1;
  int lh = l / 48, lw = l % 48;
  Ab[idx] = __float2bfloat16(basepad[((size_t)(n * 64 + o) * 50 + (lh - di + 1)) * 50 + (lw - dj + 1)]);
}

// ---------------- stage 1: QK tile GEMM + chunk-local softmax, writes P~ ------------
// grid: (qlen/64, 9 chunks). attnT rows indexed by (q - qlo).
__global__ __launch_bounds__(256) void k_qk(
    const bf16* __restrict__ Xp, const bf16* __restrict__ Kp,
    bf16* __restrict__ attnT, float* __restrict__ statsM, float* __restrict__ statsZ,
    int n, int qlo)
{
  __shared__ __align__(16) short Xs[64 * 296];   // 64 q rows x 288 k (+8 pad)
  __shared__ __align__(16) short Ks[256 * 40];   // 256 l rows x 32 k (+8 pad)
  int tid = threadIdx.x;
  int lane = tid & 63, wv = tid >> 6;
  int quad = lane >> 4, m16 = lane & 15;
  int q0 = qlo + blockIdx.x * 64;
  int l0 = blockIdx.y * 256;

  { // stage Xs (64x288)
    const short* src = (const short*)Xp + ((size_t)n * 9216 + q0) * 288;
    int row = tid >> 2, part = tid & 3;
#pragma unroll
    for (int v = 0; v < 9; v++) {
      int col = part * 72 + v * 8;
      *(short8*)&Xs[row * 296 + col] = *(const short8*)&src[(size_t)row * 288 + col];
    }
  }

  f32x4 acc[16];
#pragma unroll
  for (int t = 0; t < 16; t++) acc[t] = (f32x4){0.f, 0.f, 0.f, 0.f};

  for (int kk = 0; kk < 288; kk += 32) {
    if (kk) __syncthreads();
    { // stage Ks: one l-row per thread
      const short* src = (const short*)Kp + ((size_t)n * 2304 + l0 + tid) * 288 + kk;
#pragma unroll
      for (int v = 0; v < 4; v++)
        *(short8*)&Ks[tid * 40 + v * 8] = *(const short8*)&src[v * 8];
    }
    __syncthreads();
    short8 af = *(const short8*)&Xs[(wv * 16 + m16) * 296 + kk + quad * 8];
#pragma unroll
    for (int t = 0; t < 16; t++) {
      short8 bf = *(const short8*)&Ks[(t * 16 + m16) * 40 + quad * 8];
      acc[t] = __builtin_amdgcn_mfma_f32_16x16x32_bf16(af, bf, acc[t], 0, 0, 0);
    }
  }
  __syncthreads();  // done reading Xs/Ks; Xs reused as P~ staging below

  short* Ps = Xs;   // layout [64][264]
  float mrow[4], zrow[4];
#pragma unroll
  for (int r = 0; r < 4; r++) mrow[r] = -3.0e38f;
#pragma unroll
  for (int t = 0; t < 16; t++)
#pragma unroll
    for (int r = 0; r < 4; r++) mrow[r] = fmaxf(mrow[r], acc[t][r]);
#pragma unroll
  for (int off = 1; off < 16; off <<= 1)
#pragma unroll
    for (int r = 0; r < 4; r++) mrow[r] = fmaxf(mrow[r], __shfl_xor(mrow[r], off));
#pragma unroll
  for (int r = 0; r < 4; r++) zrow[r] = 0.f;
#pragma unroll
  for (int t = 0; t < 16; t++)
#pragma unroll
    for (int r = 0; r < 4; r++) {
      float e = __expf(acc[t][r] - mrow[r]);
      zrow[r] += e;
      Ps[(wv * 16 + quad * 4 + r) * 264 + t * 16 + m16] = f2s(e);
    }
#pragma unroll
  for (int off = 1; off < 16; off <<= 1)
#pragma unroll
    for (int r = 0; r < 4; r++) zrow[r] += __shfl_xor(zrow[r], off);
  if (m16 == 0) {
#pragma unroll
    for (int r = 0; r < 4; r++) {
      int qq = q0 + wv * 16 + quad * 4 + r;
      statsM[blockIdx.y * 9216 + qq] = mrow[r];
      statsZ[blockIdx.y * 9216 + qq] = zrow[r];
    }
  }
  __syncthreads();
  { // coalesced write of 64x256 P~ tile to attnT
    int row = tid >> 2, part = tid & 3;
    short* dst = (short*)attnT + (size_t)(q0 - qlo + row) * 2304 + l0 + part * 64;
    const short* srcp = &Ps[row * 264 + part * 64];
#pragma unroll
    for (int v = 0; v < 8; v++)
      *(short8*)&dst[v * 8] = *(const short8*)&srcp[v * 8];
  }
}

// ---------------- stage 2: combine chunk stats -> alpha[c][q] ----------------
__global__ __launch_bounds__(256) void k_alpha(
    const float* __restrict__ statsM, const float* __restrict__ statsZ,
    float* __restrict__ alpha, int qlo, int qlen)
{
  int i = blockIdx.x * 256 + threadIdx.x;
  if (i >= qlen) return;
  int q = qlo + i;
  float M = -3.0e38f;
#pragma unroll
  for (int c = 0; c < 9; c++) M = fmaxf(M, statsM[c * 9216 + q]);
  float Z = 0.f;
#pragma unroll
  for (int c = 0; c < 9; c++) Z += statsZ[c * 9216 + q] * __expf(statsM[c * 9216 + q] - M);
  float invZ = 1.f / Z;
#pragma unroll
  for (int c = 0; c < 9; c++) alpha[c * 9216 + q] = __expf(statsM[c * 9216 + q] - M) * invZ;
}

// ---------------- stage 3: PV GEMM  Y[576 x qlen] = Abase @ (P~ * alpha) ------------
// grid: (9 row-blocks of 64, qlen/256)
__global__ __launch_bounds__(256) void k_pv(
    const bf16* __restrict__ Abase, const bf16* __restrict__ attnT,
    const float* __restrict__ alpha, float* __restrict__ Y,
    int n, int qlo, int qlen)
{
  __shared__ __align__(16) short As[64 * 72];
  __shared__ __align__(16) short Bs[256 * 72];
  int tid = threadIdx.x, lane = tid & 63, wv = tid >> 6;
  int quad = lane >> 4, m16 = lane & 15;
  int wr = wv >> 1, wc = wv & 1;  // 2x2 wave grid over 64 rows x 256 cols
  int r0 = blockIdx.x * 64;
  int q0 = blockIdx.y * 256;
  f32x4 acc[2][8];
#pragma unroll
  for (int i = 0; i < 2; i++)
#pragma unroll
    for (int t = 0; t < 8; t++) acc[i][t] = (f32x4){0.f, 0.f, 0.f, 0.f};

  const short* Ab = (const short*)Abase + (size_t)n * 576 * 2304 + (size_t)r0 * 2304;
  for (int kk = 0; kk < 2304; kk += 64) {
    if (kk) __syncthreads();
    { // stage As 64x64
      int row = tid >> 2, part = tid & 3;
#pragma unroll
      for (int v = 0; v < 2; v++) {
        int col = part * 16 + v * 8;
        *(short8*)&As[row * 72 + col] = *(const short8*)&Ab[(size_t)row * 2304 + kk + col];
      }
    }
    { // stage Bs 256x64 with alpha applied (chunk index kk>>8 uniform over the 64-k window)
      int q = qlo + q0 + tid;
      float al = alpha[(kk >> 8) * 9216 + q];
      const short* src = (const short*)attnT + (size_t)(q0 + tid) * 2304 + kk;
#pragma unroll
      for (int v = 0; v < 8; v++) {
        short8 sv = *(const short8*)&src[v * 8];
        short8 dv;
#pragma unroll
        for (int j = 0; j < 8; j++) dv[j] = f2s(s2f(sv[j]) * al);
        *(short8*)&Bs[tid * 72 + v * 8] = dv;
      }
    }
    __syncthreads();
#pragma unroll
    for (int ks = 0; ks < 64; ks += 32) {
      short8 af0 = *(const short8*)&As[(wr * 32 + m16) * 72 + ks + quad * 8];
      short8 af1 = *(const short8*)&As[(wr * 32 + 16 + m16) * 72 + ks + quad * 8];
#pragma unroll
      for (int t = 0; t < 8; t++) {
        short8 bf = *(const short8*)&Bs[(wc * 128 + t * 16 + m16) * 72 + ks + quad * 8];
        acc[0][t] = __builtin_amdgcn_mfma_f32_16x16x32_bf16(af0, bf, acc[0][t], 0, 0, 0);
        acc[1][t] = __builtin_amdgcn_mfma_f32_16x16x32_bf16(af1, bf, acc[1][t], 0, 0, 0);
      }
    }
  }
#pragma unroll
  for (int i = 0; i < 2; i++)
#pragma unroll
    for (int t = 0; t < 8; t++)
#pragma unroll
      for (int r = 0; r < 4; r++) {
        int row = r0 + wr * 32 + i * 16 + quad * 4 + r;
        int col = q0 + wc * 128 + t * 16 + m16;
        Y[(size_t)row * qlen + col] = acc[i][t][r];
      }
}

// ---------------- epilogue: y = 0.25 * sum_d Y[d*64+o, q+delta] + input_l ----------
__global__ __launch_bounds__(256) void k_epi(
    const float* __restrict__ Y, const float* __restrict__ inl,
    float* __restrict__ out, int n, int q0, int qcnt, int qlo, int qlen)
{
  int i = blockIdx.x * 256 + threadIdx.x;
  if (i >= qcnt * 64) return;
  int qrel = i % qcnt, o = i / qcnt;
  int q = q0 + qrel;
  int h = q / 96, w = q % 96;
  float s = 0.f;
#pragma unroll
  for (int d = 0; d < 9; d++) {
    int di = d / 3 - 1, dj = d % 3 - 1;
    int hh = h + di, ww = w + dj;
    if (hh >= 0 && hh < 96 && ww >= 0 && ww < 96)
      s += Y[(size_t)(d * 64 + o) * qlen + (hh * 96 + ww - qlo)];
  }
  size_t oi = ((size_t)n * 64 + o) * 9216 + q;
  out[oi] = 0.25f * s + inl[oi];
}

extern "C" void kernel_launch(void* const* d_in, const int* in_sizes, int n_in,
                              void* d_out, int out_size, void* d_ws, size_t ws_size,
                              hipStream_t stream)
{
  (void)in_sizes; (void)n_in; (void)out_size;
  const float* input_l = (const float*)d_in[0];
  const float* input_s = (const float*)d_in[1];
  const float* w_mlb = (const float*)d_in[2];
  const float* b_mlb = (const float*)d_in[3];
  const float* a_mlb = (const float*)d_in[4];
  const float* w_m   = (const float*)d_in[5];
  const float* b_m   = (const float*)d_in[6];
  const float* a_m   = (const float*)d_in[7];
  const float* w_asm = (const float*)d_in[8];
  const float* b_asm = (const float*)d_in[9];
  const float* a_asm = (const float*)d_in[10];
  float* out = (float*)d_out;

  char* base = (char*)d_ws;
  size_t off = 0;
  auto carve = [&](size_t bytes) -> char* {
    char* r = base + off;
    off += (bytes + 255) & ~(size_t)255;
    return r;
  };

  float* MBpad   = (float*)carve((size_t)4 * 32 * 98 * 98 * 4);
  float* REFpad  = (float*)carve((size_t)4 * 32 * 50 * 50 * 4);
  float* BASEpad = (float*)carve((size_t)4 * 64 * 50 * 50 * 4);
  bf16*  Kp      = (bf16*)carve((size_t)4 * 2304 * 288 * 2);
  bf16*  Xp      = (bf16*)carve((size_t)4 * 9216 * 288 * 2);
  bf16*  Ab      = (bf16*)carve((size_t)4 * 576 * 2304 * 2);
  float* statsM  = (float*)carve((size_t)9 * 9216 * 4);
  float* statsZ  = (float*)carve((size_t)9 * 9216 * 4);
  float* alpha   = (float*)carve((size_t)9 * 9216 * 4);
  size_t fixedOff = off;

  // pick the coarsest query split whose attn/Y buffers fit ws
  auto need = [&](int maxlen) -> size_t {
    size_t a = ((size_t)maxlen * 2304 * 2 + 255) & ~(size_t)255;
    size_t y = ((size_t)576 * maxlen * 4 + 255) & ~(size_t)255;
    return fixedOff + a + y;
  };
  int nsplit, maxlen;
  if (need(9216) <= ws_size)      { nsplit = 1; maxlen = 9216; }
  else if (need(4864) <= ws_size) { nsplit = 2; maxlen = 4864; }
  else                            { nsplit = 4; maxlen = 2816; }

  bf16*  attnT = (bf16*)carve((size_t)maxlen * 2304 * 2);
  float* Yb    = (float*)carve((size_t)576 * maxlen * 4);

  // ---- prep (all samples) ----
  {
    int t1 = 4 * 32 * 98 * 98;
    k_conv1x1<<<dim3((t1 + 255) / 256), dim3(256), 0, stream>>>(input_l, w_mlb, b_mlb, a_mlb, MBpad, 32, 96, 96, t1);
    int t2 = 4 * 32 * 50 * 50;
    k_conv1x1<<<dim3((t2 + 255) / 256), dim3(256), 0, stream>>>(input_s, w_m, b_m, a_m, REFpad, 32, 48, 48, t2);
    int t3 = 4 * 64 * 50 * 50;
    k_conv1x1<<<dim3((t3 + 255) / 256), dim3(256), 0, stream>>>(input_s, w_asm, b_asm, a_asm, BASEpad, 64, 48, 48, t3);
    k_kp<<<dim3(2304), dim3(256), 0, stream>>>(REFpad, Kp);
    int t4 = 4 * 9216 * 288;
    k_xp<<<dim3(t4 / 256), dim3(256), 0, stream>>>(MBpad, Xp, t4);
    int t5 = 4 * 576 * 2304;
    k_abase<<<dim3(t5 / 256), dim3(256), 0, stream>>>(BASEpad, Ab, t5);
  }

  // ---- attention per (sample, query band) ----
  int psplit = 9216 / nsplit;
  for (int n = 0; n < 4; n++) {
    for (int s = 0; s < nsplit; s++) {
      int q0 = s * psplit;
      int qlo = q0 - 256; if (qlo < 0) qlo = 0;
      int qhi = q0 + psplit + 256; if (qhi > 9216) qhi = 9216;
      int qlen = qhi - qlo;  // multiple of 256 by construction
      k_qk<<<dim3(qlen / 64, 9), dim3(256), 0, stream>>>(Xp, Kp, attnT, statsM, statsZ, n, qlo);
      k_alpha<<<dim3(qlen / 256), dim3(256), 0, stream>>>(statsM, statsZ, alpha, qlo, qlen);
      k_pv<<<dim3(9, qlen / 256), dim3(256), 0, stream>>>(Ab, attnT, alpha, Yb, n, qlo, qlen);
      k_epi<<<dim3(psplit * 64 / 256), dim3(256), 0, stream>>>(Yb, input_l, out, n, q0, psplit, qlo, qlen);
    }
  }
}

// Round 3
// 947.109 us; speedup vs baseline: 1.0165x; 1.0165x over previous
//
#include <hip/hip_runtime.h>
#include <hip/hip_bf16.h>
#include <cstdint>
#include <cstddef>

typedef __hip_bfloat16 bf16;
using short8 = __attribute__((ext_vector_type(8))) short;
using f32x4  = __attribute__((ext_vector_type(4))) float;
using float4v = __attribute__((ext_vector_type(4))) float;

__device__ __forceinline__ float s2f(short s) {
  unsigned u = ((unsigned)(unsigned short)s) << 16;
  return __builtin_bit_cast(float, u);
}
__device__ __forceinline__ short f2s(float f) {  // RNE f32->bf16
  unsigned u = __builtin_bit_cast(unsigned, f);
  u += 0x7fffu + ((u >> 16) & 1u);
  return (short)(u >> 16);
}

// ---------------- 1x1 conv + PReLU into zero-padded (+1 ring) f32 output ------------
__global__ __launch_bounds__(256) void k_conv1x1(
    const float* __restrict__ in, const float* __restrict__ w,
    const float* __restrict__ bias, const float* __restrict__ aprm,
    float* __restrict__ out, int Cout, int Hin, int Win, int total)
{
  int idx = blockIdx.x * 256 + threadIdx.x;
  if (idx >= total) return;
  int Wp = Win + 2, Hp = Hin + 2;
  int x = idx % Wp;
  int t = idx / Wp;
  int y = t % Hp; t /= Hp;
  int o = t % Cout; int n = t / Cout;
  if (x == 0 || x == Wp - 1 || y == 0 || y == Hp - 1) { out[idx] = 0.0f; return; }
  int cs = Hin * Win;
  const float* ip = in + (size_t)n * 64 * cs + (size_t)(y - 1) * Win + (x - 1);
  const float* wp = w + o * 64;
  float s = bias[o];
#pragma unroll 16
  for (int ci = 0; ci < 64; ci++)
    s += wp[ci] * ip[(size_t)ci * cs];
  float a = aprm[0];
  out[idx] = s >= 0.0f ? s : a * s;
}

// ---------------- key patches, L2-normalized, softmax scale 10 folded in ------------
__global__ __launch_bounds__(256) void k_kp(const float* __restrict__ refpad, bf16* __restrict__ Kp)
{
  int wid = blockIdx.x * 4 + (threadIdx.x >> 6);
  int lane = threadIdx.x & 63;
  if (wid >= 4 * 2304) return;
  int n = wid / 2304, l = wid % 2304, lh = l / 48, lw = l % 48;
  float v[5]; float ss = 0.f;
#pragma unroll
  for (int i = 0; i < 5; i++) {
    int k = lane + 64 * i; v[i] = 0.f;
    if (k < 288) {
      int c = k / 9, rr = (k % 9) / 3, sc = k % 3;
      v[i] = refpad[((size_t)(n * 32 + c) * 50 + lh + rr) * 50 + lw + sc];
      ss += v[i] * v[i];
    }
  }
#pragma unroll
  for (int off = 32; off; off >>= 1) ss += __shfl_xor(ss, off);
  float inv = 10.f / (sqrtf(ss) + 1e-4f);
#pragma unroll
  for (int i = 0; i < 5; i++) {
    int k = lane + 64 * i;
    if (k < 288) Kp[(size_t)wid * 288 + k] = __float2bfloat16(v[i] * inv);
  }
}

// ---------------- query patches Xp[n][p][288], bf16 ----------------
__global__ __launch_bounds__(256) void k_xp(const float* __restrict__ mbpad, bf16* __restrict__ Xp, int total)
{
  int idx = blockIdx.x * 256 + threadIdx.x;
  if (idx >= total) return;
  int k = idx % 288; int p = (idx / 288) % 9216; int n = idx / (288 * 9216);
  int c = k / 9, rr = (k % 9) / 3, sc = k % 3;
  int ph = p / 96, pw = p % 96;
  Xp[idx] = __float2bfloat16(mbpad[((size_t)(n * 32 + c) * 98 + ph + rr) * 98 + pw + sc]);
}

// ---------------- base value matrix Bb[n][o][l] (o-major, l contiguous), bf16 -------
__global__ __launch_bounds__(256) void k_baseT(const float* __restrict__ basepad, bf16* __restrict__ Bb, int total)
{
  int idx = blockIdx.x * 256 + threadIdx.x;
  if (idx >= total) return;
  int l = idx % 2304; int o = (idx / 2304) % 64; int n = idx / (2304 * 64);
  int lh = l / 48, lw = l % 48;
  Bb[idx] = __float2bfloat16(basepad[((size_t)(n * 64 + o) * 50 + lh + 1) * 50 + lw + 1]);
}

// ---------------- stage 1: QK tile GEMM + chunk-local softmax, writes P~ ------------
// block: 128 q x 256 l; 4 waves, each 32 q. A-frags direct from global (L2-hot Xp).
__global__ __launch_bounds__(256, 2) void k_qk(
    const bf16* __restrict__ Xp, const bf16* __restrict__ Kp,
    bf16* __restrict__ attnT, float* __restrict__ statsM, float* __restrict__ statsZ,
    int n, int qlo)
{
  __shared__ __align__(16) short smem[64 * 264];  // union: Ks (256x40) then Ps (64x264)
  short* Ks = smem;
  short* Ps = smem;
  int tid = threadIdx.x;
  int lane = tid & 63, wv = tid >> 6;
  int quad = lane >> 4, m16 = lane & 15;
  int q0 = qlo + blockIdx.x * 128;
  int l0 = blockIdx.y * 256;

  f32x4 acc[2][16];
#pragma unroll
  for (int mi = 0; mi < 2; mi++)
#pragma unroll
    for (int t = 0; t < 16; t++) acc[mi][t] = (f32x4){0.f, 0.f, 0.f, 0.f};

  const short* Xrow = (const short*)Xp + ((size_t)n * 9216 + q0 + wv * 32 + m16) * 288;
  const short* Ksrc = (const short*)Kp + ((size_t)n * 2304 + l0) * 288;
  int srow = tid >> 2, scol = (tid & 3) * 8;

  for (int kk = 0; kk < 288; kk += 32) {
    if (kk) __syncthreads();
#pragma unroll
    for (int p = 0; p < 4; p++)
      *(short8*)&Ks[(srow + 64 * p) * 40 + scol] =
          *(const short8*)&Ksrc[(size_t)(srow + 64 * p) * 288 + kk + scol];
    __syncthreads();
    short8 a0 = *(const short8*)&Xrow[kk + quad * 8];
    short8 a1 = *(const short8*)&Xrow[16 * 288 + kk + quad * 8];
#pragma unroll
    for (int t = 0; t < 16; t++) {
      short8 b = *(const short8*)&Ks[(t * 16 + m16) * 40 + quad * 8];
      acc[0][t] = __builtin_amdgcn_mfma_f32_16x16x32_bf16(a0, b, acc[0][t], 0, 0, 0);
      acc[1][t] = __builtin_amdgcn_mfma_f32_16x16x32_bf16(a1, b, acc[1][t], 0, 0, 0);
    }
  }

  // chunk-local softmax stats (row = q, reduce over cols = m16 lanes)
  float mrow[2][4], zrow[2][4];
#pragma unroll
  for (int mi = 0; mi < 2; mi++)
#pragma unroll
    for (int r = 0; r < 4; r++) mrow[mi][r] = -3.0e38f;
#pragma unroll
  for (int mi = 0; mi < 2; mi++)
#pragma unroll
    for (int t = 0; t < 16; t++)
#pragma unroll
      for (int r = 0; r < 4; r++) mrow[mi][r] = fmaxf(mrow[mi][r], acc[mi][t][r]);
#pragma unroll
  for (int off = 1; off < 16; off <<= 1)
#pragma unroll
    for (int mi = 0; mi < 2; mi++)
#pragma unroll
      for (int r = 0; r < 4; r++) mrow[mi][r] = fmaxf(mrow[mi][r], __shfl_xor(mrow[mi][r], off));
#pragma unroll
  for (int mi = 0; mi < 2; mi++)
#pragma unroll
    for (int r = 0; r < 4; r++) zrow[mi][r] = 0.f;
#pragma unroll
  for (int mi = 0; mi < 2; mi++)
#pragma unroll
    for (int t = 0; t < 16; t++)
#pragma unroll
      for (int r = 0; r < 4; r++) {
        float e = __expf(acc[mi][t][r] - mrow[mi][r]);
        acc[mi][t][r] = e;
        zrow[mi][r] += e;
      }
#pragma unroll
  for (int off = 1; off < 16; off <<= 1)
#pragma unroll
    for (int mi = 0; mi < 2; mi++)
#pragma unroll
      for (int r = 0; r < 4; r++) zrow[mi][r] += __shfl_xor(zrow[mi][r], off);
  if (m16 == 0) {
#pragma unroll
    for (int mi = 0; mi < 2; mi++)
#pragma unroll
      for (int r = 0; r < 4; r++) {
        int qq = q0 + wv * 32 + mi * 16 + quad * 4 + r;
        statsM[blockIdx.y * 9216 + qq] = mrow[mi][r];
        statsZ[blockIdx.y * 9216 + qq] = zrow[mi][r];
      }
  }

  // write P~ in two 64-row halves through LDS (coalesced global stores)
#pragma unroll
  for (int h = 0; h < 2; h++) {
    __syncthreads();
    if ((wv >> 1) == h) {
#pragma unroll
      for (int mi = 0; mi < 2; mi++)
#pragma unroll
        for (int t = 0; t < 16; t++)
#pragma unroll
          for (int r = 0; r < 4; r++)
            Ps[((wv & 1) * 32 + mi * 16 + quad * 4 + r) * 264 + t * 16 + m16] = f2s(acc[mi][t][r]);
    }
    __syncthreads();
    int row = tid >> 2, part = tid & 3;
    short* dst = (short*)attnT + (size_t)(q0 - qlo + h * 64 + row) * 2304 + l0 + part * 64;
    const short* sp = &Ps[row * 264 + part * 64];
#pragma unroll
    for (int v = 0; v < 8; v++)
      *(short8*)&dst[v * 8] = *(const short8*)&sp[v * 8];
  }
}

// ---------------- stage 2: combine chunk stats -> alpha[c][q] ----------------
__global__ __launch_bounds__(256) void k_alpha(
    const float* __restrict__ statsM, const float* __restrict__ statsZ,
    float* __restrict__ alpha, int qlo, int qlen)
{
  int i = blockIdx.x * 256 + threadIdx.x;
  if (i >= qlen) return;
  int q = qlo + i;
  float M = -3.0e38f;
#pragma unroll
  for (int c = 0; c < 9; c++) M = fmaxf(M, statsM[c * 9216 + q]);
  float Z = 0.f;
#pragma unroll
  for (int c = 0; c < 9; c++) Z += statsZ[c * 9216 + q] * __expf(statsM[c * 9216 + q] - M);
  float invZ = 1.f / Z;
#pragma unroll
  for (int c = 0; c < 9; c++) alpha[c * 9216 + q] = __expf(statsM[c * 9216 + q] - M) * invZ;
}

// ---------------- stage 3: diagonal-shift stencil  A2[l,q] = sum_d attn[l+ds, q+dl] --
// one block per output q row; alpha folded in. A2 stored q-major band-local.
__global__ __launch_bounds__(256) void k_a2(
    const bf16* __restrict__ attnT, const float* __restrict__ alpha,
    bf16* __restrict__ A2, int q0, int qlo, int qhi)
{
  __shared__ float al[9][9];
  int q = q0 + blockIdx.x;
  int tid = threadIdx.x;
  int h = q / 96, w = q % 96;
  if (tid < 81) {
    int c = tid / 9, d = tid % 9;
    int di = d / 3 - 1, dj = d % 3 - 1;
    int qs = q + di * 96 + dj;
    qs = qs < qlo ? qlo : (qs >= qhi ? qhi - 1 : qs);
    al[c][d] = alpha[c * 9216 + qs];
  }
  __syncthreads();
  bool hok0 = h > 0, hok2 = h < 95;
  bool wok0 = w > 0, wok2 = w < 95;
  const short* att = (const short*)attnT;
#pragma unroll
  for (int i = 0; i < 9; i++) {
    int l = tid + 256 * i;
    int lh = l / 48, lw = l - lh * 48;
    float s = 0.f;
#pragma unroll
    for (int di = -1; di <= 1; di++) {
      if (di == -1 && (!hok0 || lh == 0)) continue;
      if (di == 1 && (!hok2 || lh == 47)) continue;
#pragma unroll
      for (int dj = -1; dj <= 1; dj++) {
        if (dj == -1 && (!wok0 || lw == 0)) continue;
        if (dj == 1 && (!wok2 || lw == 47)) continue;
        int ls = l + di * 48 + dj;
        int qs = q + di * 96 + dj;
        int d = (di + 1) * 3 + dj + 1;
        s += s2f(att[(size_t)(qs - qlo) * 2304 + ls]) * al[ls >> 8][d];
      }
    }
    ((short*)A2)[(size_t)(q - q0) * 2304 + l] = f2s(s);
  }
}

// ---------------- stage 4: PV GEMM  out[o,q] = 0.25 * (Bb @ A2)[o,q] + input_l -------
// block: 128 q (M-dim) x 64 o (N-dim); C computed as C[m=q][n=o], transposed via LDS.
__global__ __launch_bounds__(256) void k_pv2(
    const bf16* __restrict__ A2, const bf16* __restrict__ Bb,
    const float* __restrict__ inl, float* __restrict__ out,
    int n, int q0base)
{
  __shared__ __align__(16) short As2[128 * 72];
  __shared__ __align__(16) short Bs2[64 * 72];
  __shared__ float Cst[4][64][20];
  int tid = threadIdx.x, lane = tid & 63, wv = tid >> 6;
  int quad = lane >> 4, m16 = lane & 15;
  int qb = blockIdx.x * 128;
  f32x4 acc[2][4];
#pragma unroll
  for (int i = 0; i < 2; i++)
#pragma unroll
    for (int t = 0; t < 4; t++) acc[i][t] = (f32x4){0.f, 0.f, 0.f, 0.f};

  const short* Ap = (const short*)A2 + (size_t)qb * 2304;
  const short* Bp = (const short*)Bb + (size_t)n * 64 * 2304;
  int arow = tid >> 1, acol = (tid & 1) * 32;
  int brow = tid >> 2, bcol = (tid & 3) * 16;

  for (int kk = 0; kk < 2304; kk += 64) {
    if (kk) __syncthreads();
#pragma unroll
    for (int v = 0; v < 4; v++)
      *(short8*)&As2[arow * 72 + acol + v * 8] = *(const short8*)&Ap[(size_t)arow * 2304 + kk + acol + v * 8];
#pragma unroll
    for (int v = 0; v < 2; v++)
      *(short8*)&Bs2[brow * 72 + bcol + v * 8] = *(const short8*)&Bp[(size_t)brow * 2304 + kk + bcol + v * 8];
    __syncthreads();
#pragma unroll
    for (int ks = 0; ks < 64; ks += 32) {
      short8 a0 = *(const short8*)&As2[(wv * 32 + m16) * 72 + ks + quad * 8];
      short8 a1 = *(const short8*)&As2[(wv * 32 + 16 + m16) * 72 + ks + quad * 8];
#pragma unroll
      for (int ni = 0; ni < 4; ni++) {
        short8 b = *(const short8*)&Bs2[(ni * 16 + m16) * 72 + ks + quad * 8];
        acc[0][ni] = __builtin_amdgcn_mfma_f32_16x16x32_bf16(a0, b, acc[0][ni], 0, 0, 0);
        acc[1][ni] = __builtin_amdgcn_mfma_f32_16x16x32_bf16(a1, b, acc[1][ni], 0, 0, 0);
      }
    }
  }

  // epilogue: transpose C[q][o] -> out[o][q] via per-wave LDS, fuse 0.25x + residual
#pragma unroll
  for (int half = 0; half < 2; half++) {
    __syncthreads();
#pragma unroll
    for (int ni = 0; ni < 4; ni++)
#pragma unroll
      for (int r = 0; r < 4; r++)
        Cst[wv][ni * 16 + m16][quad * 4 + r] = acc[half][ni][r];
    __syncthreads();
    int qg = q0base + qb + wv * 32 + half * 16 + (lane & 3) * 4;
#pragma unroll
    for (int rep = 0; rep < 4; rep++) {
      int o = rep * 16 + (lane >> 2);
      float4v c4 = *(float4v*)&Cst[wv][o][(lane & 3) * 4];
      size_t oid = ((size_t)(n * 64 + o)) * 9216 + qg;
      float4v r4 = *(const float4v*)&inl[oid];
      float4v y;
#pragma unroll
      for (int j = 0; j < 4; j++) y[j] = 0.25f * c4[j] + r4[j];
      *(float4v*)&out[oid] = y;
    }
  }
}

extern "C" void kernel_launch(void* const* d_in, const int* in_sizes, int n_in,
                              void* d_out, int out_size, void* d_ws, size_t ws_size,
                              hipStream_t stream)
{
  (void)in_sizes; (void)n_in; (void)out_size;
  const float* input_l = (const float*)d_in[0];
  const float* input_s = (const float*)d_in[1];
  const float* w_mlb = (const float*)d_in[2];
  const float* b_mlb = (const float*)d_in[3];
  const float* a_mlb = (const float*)d_in[4];
  const float* w_m   = (const float*)d_in[5];
  const float* b_m   = (const float*)d_in[6];
  const float* a_m   = (const float*)d_in[7];
  const float* w_asm = (const float*)d_in[8];
  const float* b_asm = (const float*)d_in[9];
  const float* a_asm = (const float*)d_in[10];
  float* out = (float*)d_out;

  char* base = (char*)d_ws;
  size_t off = 0;
  auto carve = [&](size_t bytes) -> char* {
    char* r = base + off;
    off += (bytes + 255) & ~(size_t)255;
    return r;
  };

  float* MBpad   = (float*)carve((size_t)4 * 32 * 98 * 98 * 4);
  float* REFpad  = (float*)carve((size_t)4 * 32 * 50 * 50 * 4);
  float* BASEpad = (float*)carve((size_t)4 * 64 * 50 * 50 * 4);
  bf16*  Kp      = (bf16*)carve((size_t)4 * 2304 * 288 * 2);
  bf16*  Xp      = (bf16*)carve((size_t)4 * 9216 * 288 * 2);
  bf16*  Bb     = (bf16*)carve((size_t)4 * 64 * 2304 * 2);
  float* statsM  = (float*)carve((size_t)9 * 9216 * 4);
  float* statsZ  = (float*)carve((size_t)9 * 9216 * 4);
  float* alpha   = (float*)carve((size_t)9 * 9216 * 4);
  size_t fixedOff = off;

  // pick the coarsest query split whose attnT/A2 buffers fit ws
  auto need = [&](int qmax, int psplit) -> size_t {
    size_t a = ((size_t)qmax * 2304 * 2 + 255) & ~(size_t)255;
    size_t b2 = ((size_t)psplit * 2304 * 2 + 255) & ~(size_t)255;
    return fixedOff + a + b2;
  };
  int nsplit, qmax, psplit;
  if (need(9216, 9216) <= ws_size)      { nsplit = 1; qmax = 9216; psplit = 9216; }
  else if (need(5120, 4608) <= ws_size) { nsplit = 2; qmax = 5120; psplit = 4608; }
  else                                  { nsplit = 4; qmax = 2816; psplit = 2304; }

  bf16* attnT = (bf16*)carve((size_t)qmax * 2304 * 2);
  bf16* A2    = (bf16*)carve((size_t)psplit * 2304 * 2);

  // ---- prep (all samples) ----
  {
    int t1 = 4 * 32 * 98 * 98;
    k_conv1x1<<<dim3((t1 + 255) / 256), dim3(256), 0, stream>>>(input_l, w_mlb, b_mlb, a_mlb, MBpad, 32, 96, 96, t1);
    int t2 = 4 * 32 * 50 * 50;
    k_conv1x1<<<dim3((t2 + 255) / 256), dim3(256), 0, stream>>>(input_s, w_m, b_m, a_m, REFpad, 32, 48, 48, t2);
    int t3 = 4 * 64 * 50 * 50;
    k_conv1x1<<<dim3((t3 + 255) / 256), dim3(256), 0, stream>>>(input_s, w_asm, b_asm, a_asm, BASEpad, 64, 48, 48, t3);
    k_kp<<<dim3(2304), dim3(256), 0, stream>>>(REFpad, Kp);
    int t4 = 4 * 9216 * 288;
    k_xp<<<dim3(t4 / 256), dim3(256), 0, stream>>>(MBpad, Xp, t4);
    int t5 = 4 * 64 * 2304;
    k_baseT<<<dim3(t5 / 256), dim3(256), 0, stream>>>(BASEpad, Bb, t5);
  }

  // ---- attention per (sample, query band) ----
  for (int n = 0; n < 4; n++) {
    for (int s = 0; s < nsplit; s++) {
      int q0 = s * psplit;
      int qlo = q0 - 256; if (qlo < 0) qlo = 0;
      int qhi = q0 + psplit + 256; if (qhi > 9216) qhi = 9216;
      int qlen = qhi - qlo;  // multiple of 256 by construction
      k_qk<<<dim3(qlen / 128, 9), dim3(256), 0, stream>>>(Xp, Kp, attnT, statsM, statsZ, n, qlo);
      k_alpha<<<dim3(qlen / 256), dim3(256), 0, stream>>>(statsM, statsZ, alpha, qlo, qlen);
      k_a2<<<dim3(psplit), dim3(256), 0, stream>>>(attnT, alpha, A2, q0, qlo, qhi);
      k_pv2<<<dim3(psplit / 128), dim3(256), 0, stream>>>(A2, Bb, input_l, out, n, q0);
    }
  }
}

// Round 4
// 772.361 us; speedup vs baseline: 1.2465x; 1.2263x over previous
//
#include <hip/hip_runtime.h>
#include <hip/hip_bf16.h>
#include <cstdint>
#include <cstddef>

typedef __hip_bfloat16 bf16;
using short8 = __attribute__((ext_vector_type(8))) short;
using f32x4  = __attribute__((ext_vector_type(4))) float;
using float4v = __attribute__((ext_vector_type(4))) float;
using uint4v  = __attribute__((ext_vector_type(4))) unsigned int;

__device__ __forceinline__ float s2f(short s) {
  unsigned u = ((unsigned)(unsigned short)s) << 16;
  return __builtin_bit_cast(float, u);
}
__device__ __forceinline__ short f2s(float f) {  // RNE f32->bf16
  unsigned u = __builtin_bit_cast(unsigned, f);
  u += 0x7fffu + ((u >> 16) & 1u);
  return (short)(u >> 16);
}

// ---------------- 1x1 conv + PReLU into zero-padded (+1 ring) f32 output ------------
__global__ __launch_bounds__(256) void k_conv1x1(
    const float* __restrict__ in, const float* __restrict__ w,
    const float* __restrict__ bias, const float* __restrict__ aprm,
    float* __restrict__ out, int Cout, int Hin, int Win, int total)
{
  int idx = blockIdx.x * 256 + threadIdx.x;
  if (idx >= total) return;
  int Wp = Win + 2, Hp = Hin + 2;
  int x = idx % Wp;
  int t = idx / Wp;
  int y = t % Hp; t /= Hp;
  int o = t % Cout; int n = t / Cout;
  if (x == 0 || x == Wp - 1 || y == 0 || y == Hp - 1) { out[idx] = 0.0f; return; }
  int cs = Hin * Win;
  const float* ip = in + (size_t)n * 64 * cs + (size_t)(y - 1) * Win + (x - 1);
  const float* wp = w + o * 64;
  float s = bias[o];
#pragma unroll 16
  for (int ci = 0; ci < 64; ci++)
    s += wp[ci] * ip[(size_t)ci * cs];
  float a = aprm[0];
  out[idx] = s >= 0.0f ? s : a * s;
}

// ---------------- key patches, L2-normalized, softmax scale 10 folded in ------------
__global__ __launch_bounds__(256) void k_kp(const float* __restrict__ refpad, bf16* __restrict__ Kp)
{
  int wid = blockIdx.x * 4 + (threadIdx.x >> 6);
  int lane = threadIdx.x & 63;
  if (wid >= 4 * 2304) return;
  int n = wid / 2304, l = wid % 2304, lh = l / 48, lw = l % 48;
  float v[5]; float ss = 0.f;
#pragma unroll
  for (int i = 0; i < 5; i++) {
    int k = lane + 64 * i; v[i] = 0.f;
    if (k < 288) {
      int c = k / 9, rr = (k % 9) / 3, sc = k % 3;
      v[i] = refpad[((size_t)(n * 32 + c) * 50 + lh + rr) * 50 + lw + sc];
      ss += v[i] * v[i];
    }
  }
#pragma unroll
  for (int off = 32; off; off >>= 1) ss += __shfl_xor(ss, off);
  float inv = 10.f / (sqrtf(ss) + 1e-4f);
#pragma unroll
  for (int i = 0; i < 5; i++) {
    int k = lane + 64 * i;
    if (k < 288) Kp[(size_t)wid * 288 + k] = __float2bfloat16(v[i] * inv);
  }
}

// ---------------- query patches Xp[n][p][288], bf16 ----------------
__global__ __launch_bounds__(256) void k_xp(const float* __restrict__ mbpad, bf16* __restrict__ Xp, int total)
{
  int idx = blockIdx.x * 256 + threadIdx.x;
  if (idx >= total) return;
  int k = idx % 288; int p = (idx / 288) % 9216; int n = idx / (288 * 9216);
  int c = k / 9, rr = (k % 9) / 3, sc = k % 3;
  int ph = p / 96, pw = p % 96;
  Xp[idx] = __float2bfloat16(mbpad[((size_t)(n * 32 + c) * 98 + ph + rr) * 98 + pw + sc]);
}

// ---------------- base value matrix Bb[n][o][l] (o-major, l contiguous), bf16 -------
__global__ __launch_bounds__(256) void k_baseT(const float* __restrict__ basepad, bf16* __restrict__ Bb, int total)
{
  int idx = blockIdx.x * 256 + threadIdx.x;
  if (idx >= total) return;
  int l = idx % 2304; int o = (idx / 2304) % 64; int n = idx / (2304 * 64);
  int lh = l / 48, lw = l % 48;
  Bb[idx] = __float2bfloat16(basepad[((size_t)(n * 64 + o) * 50 + lh + 1) * 50 + lw + 1]);
}

// ---------------- stage 1: QK tile GEMM + chunk-local softmax, writes P~ ------------
// block: 128 q x 256 l; 4 waves, each 32 q. A-frags direct from global (L2-hot Xp).
__global__ __launch_bounds__(256, 2) void k_qk(
    const bf16* __restrict__ Xp, const bf16* __restrict__ Kp,
    bf16* __restrict__ attnT, float* __restrict__ statsM, float* __restrict__ statsZ,
    int n, int qlo)
{
  __shared__ __align__(16) short smem[64 * 264];  // union: Ks (256x40) then Ps (64x264)
  short* Ks = smem;
  short* Ps = smem;
  int tid = threadIdx.x;
  int lane = tid & 63, wv = tid >> 6;
  int quad = lane >> 4, m16 = lane & 15;
  int q0 = qlo + blockIdx.x * 128;
  int l0 = blockIdx.y * 256;

  f32x4 acc[2][16];
#pragma unroll
  for (int mi = 0; mi < 2; mi++)
#pragma unroll
    for (int t = 0; t < 16; t++) acc[mi][t] = (f32x4){0.f, 0.f, 0.f, 0.f};

  const short* Xrow = (const short*)Xp + ((size_t)n * 9216 + q0 + wv * 32 + m16) * 288;
  const short* Ksrc = (const short*)Kp + ((size_t)n * 2304 + l0) * 288;
  int srow = tid >> 2, scol = (tid & 3) * 8;

  for (int kk = 0; kk < 288; kk += 32) {
    if (kk) __syncthreads();
#pragma unroll
    for (int p = 0; p < 4; p++)
      *(short8*)&Ks[(srow + 64 * p) * 40 + scol] =
          *(const short8*)&Ksrc[(size_t)(srow + 64 * p) * 288 + kk + scol];
    __syncthreads();
    short8 a0 = *(const short8*)&Xrow[kk + quad * 8];
    short8 a1 = *(const short8*)&Xrow[16 * 288 + kk + quad * 8];
#pragma unroll
    for (int t = 0; t < 16; t++) {
      short8 b = *(const short8*)&Ks[(t * 16 + m16) * 40 + quad * 8];
      acc[0][t] = __builtin_amdgcn_mfma_f32_16x16x32_bf16(a0, b, acc[0][t], 0, 0, 0);
      acc[1][t] = __builtin_amdgcn_mfma_f32_16x16x32_bf16(a1, b, acc[1][t], 0, 0, 0);
    }
  }

  // chunk-local softmax stats (row = q, reduce over cols = m16 lanes)
  float mrow[2][4], zrow[2][4];
#pragma unroll
  for (int mi = 0; mi < 2; mi++)
#pragma unroll
    for (int r = 0; r < 4; r++) mrow[mi][r] = -3.0e38f;
#pragma unroll
  for (int mi = 0; mi < 2; mi++)
#pragma unroll
    for (int t = 0; t < 16; t++)
#pragma unroll
      for (int r = 0; r < 4; r++) mrow[mi][r] = fmaxf(mrow[mi][r], acc[mi][t][r]);
#pragma unroll
  for (int off = 1; off < 16; off <<= 1)
#pragma unroll
    for (int mi = 0; mi < 2; mi++)
#pragma unroll
      for (int r = 0; r < 4; r++) mrow[mi][r] = fmaxf(mrow[mi][r], __shfl_xor(mrow[mi][r], off));
#pragma unroll
  for (int mi = 0; mi < 2; mi++)
#pragma unroll
    for (int r = 0; r < 4; r++) zrow[mi][r] = 0.f;
#pragma unroll
  for (int mi = 0; mi < 2; mi++)
#pragma unroll
    for (int t = 0; t < 16; t++)
#pragma unroll
      for (int r = 0; r < 4; r++) {
        float e = __expf(acc[mi][t][r] - mrow[mi][r]);
        acc[mi][t][r] = e;
        zrow[mi][r] += e;
      }
#pragma unroll
  for (int off = 1; off < 16; off <<= 1)
#pragma unroll
    for (int mi = 0; mi < 2; mi++)
#pragma unroll
      for (int r = 0; r < 4; r++) zrow[mi][r] += __shfl_xor(zrow[mi][r], off);
  if (m16 == 0) {
#pragma unroll
    for (int mi = 0; mi < 2; mi++)
#pragma unroll
      for (int r = 0; r < 4; r++) {
        int qq = q0 + wv * 32 + mi * 16 + quad * 4 + r;
        statsM[blockIdx.y * 9216 + qq] = mrow[mi][r];
        statsZ[blockIdx.y * 9216 + qq] = zrow[mi][r];
      }
  }

  // write P~ in two 64-row halves through LDS (coalesced global stores)
#pragma unroll
  for (int h = 0; h < 2; h++) {
    __syncthreads();
    if ((wv >> 1) == h) {
#pragma unroll
      for (int mi = 0; mi < 2; mi++)
#pragma unroll
        for (int t = 0; t < 16; t++)
#pragma unroll
          for (int r = 0; r < 4; r++)
            Ps[((wv & 1) * 32 + mi * 16 + quad * 4 + r) * 264 + t * 16 + m16] = f2s(acc[mi][t][r]);
    }
    __syncthreads();
    int row = tid >> 2, part = tid & 3;
    short* dst = (short*)attnT + (size_t)(q0 - qlo + h * 64 + row) * 2304 + l0 + part * 64;
    const short* sp = &Ps[row * 264 + part * 64];
#pragma unroll
    for (int v = 0; v < 8; v++)
      *(short8*)&dst[v * 8] = *(const short8*)&sp[v * 8];
  }
}

// ---- stage 2: combine chunk stats -> alpha, then normalize attnT row in place ------
// one block per band row; W[l,q] = P~[l,q] * alpha[c(l)][q]
__global__ __launch_bounds__(256) void k_alpha2(
    const float* __restrict__ statsM, const float* __restrict__ statsZ,
    bf16* __restrict__ attnT, int qlo)
{
  __shared__ float sal[9];
  int i = blockIdx.x;
  int q = qlo + i;
  int tid = threadIdx.x;
  if (tid == 0) {
    float m[9], e[9];
    float M = -3.0e38f;
#pragma unroll
    for (int c = 0; c < 9; c++) { m[c] = statsM[c * 9216 + q]; M = fmaxf(M, m[c]); }
    float Z = 0.f;
#pragma unroll
    for (int c = 0; c < 9; c++) { e[c] = __expf(m[c] - M); Z += statsZ[c * 9216 + q] * e[c]; }
    float invZ = 1.f / Z;
#pragma unroll
    for (int c = 0; c < 9; c++) sal[c] = e[c] * invZ;
  }
  __syncthreads();
  short* row = (short*)attnT + (size_t)i * 2304;
  for (int g = tid; g < 288; g += 256) {
    float al = sal[g >> 5];          // group of 8 never crosses a 256-chunk boundary
    short8 v = *(short8*)&row[g * 8];
    short8 o;
#pragma unroll
    for (int k = 0; k < 8; k++) o[k] = f2s(s2f(v[k]) * al);
    *(short8*)&row[g * 8] = o;
  }
}

// ---- stage 3: pure 9-point diagonal stencil  A2[l,q] = sum_d W[l+dl, q+dq] --------
// thread = 8 consecutive l of one q row; aligned uint4 loads + funnel shifts.
__global__ __launch_bounds__(256) void k_a2(
    const bf16* __restrict__ attnT, bf16* __restrict__ A2,
    int q0, int qlo)
{
  int g = blockIdx.x * 256 + threadIdx.x;
  int qrel = g / 288;                 // 288 groups of 8 per q row
  int j = g - qrel * 288;
  int l0 = j * 8;
  int q = q0 + qrel;
  int h = q / 96, w = q - h * 96;
  int lh = l0 / 48, lw0 = l0 - lh * 48;
  const short* att = (const short*)attnT;
  float acc[8];
#pragma unroll
  for (int k = 0; k < 8; k++) acc[k] = 0.f;
#pragma unroll
  for (int di = -1; di <= 1; di++) {
    int hh = h + di, lhh = lh + di;
    if (hh < 0 || hh >= 96 || lhh < 0 || lhh >= 48) continue;
    int lb = l0 + 48 * di;            // multiple of 8 -> 16B aligned
    const short* r0 = att + (size_t)(q + 96 * di - qlo) * 2304;
    { // dj = 0 (never l-masked: lw in [0,47])
      uint4v V = *(const uint4v*)(r0 + lb);
#pragma unroll
      for (int k = 0; k < 4; k++) {
        unsigned dw = V[k];
        acc[2 * k]     += __builtin_bit_cast(float, dw << 16);
        acc[2 * k + 1] += __builtin_bit_cast(float, dw & 0xFFFF0000u);
      }
    }
    if (w > 0) { // dj = -1: window shorts [lb-1 .. lb+6] of row q'-1
      const short* rm = r0 - 2304;
      uint4v V = *(const uint4v*)(rm + lb);
      unsigned P = *(const unsigned*)(rm + lb - 2);
      unsigned w0 = (P >> 16) | (V[0] << 16);
      if (lw0 == 0) w0 &= 0xFFFF0000u;     // element 0 would wrap to prev lh row
      unsigned wd1 = (V[0] >> 16) | (V[1] << 16);
      unsigned wd2 = (V[1] >> 16) | (V[2] << 16);
      unsigned wd3 = (V[2] >> 16) | (V[3] << 16);
      unsigned wd[4] = { w0, wd1, wd2, wd3 };
#pragma unroll
      for (int k = 0; k < 4; k++) {
        acc[2 * k]     += __builtin_bit_cast(float, wd[k] << 16);
        acc[2 * k + 1] += __builtin_bit_cast(float, wd[k] & 0xFFFF0000u);
      }
    }
    if (w < 95) { // dj = +1: window shorts [lb+1 .. lb+8] of row q'+1
      const short* rp = r0 + 2304;
      uint4v V = *(const uint4v*)(rp + lb);
      unsigned N = *(const unsigned*)(rp + lb + 8);
      unsigned w3 = (V[3] >> 16) | (N << 16);
      if (lw0 == 40) w3 &= 0x0000FFFFu;    // element 7 would wrap to next lh row
      unsigned wd0 = (V[0] >> 16) | (V[1] << 16);
      unsigned wd1 = (V[1] >> 16) | (V[2] << 16);
      unsigned wd2 = (V[2] >> 16) | (V[3] << 16);
      unsigned wd[4] = { wd0, wd1, wd2, w3 };
#pragma unroll
      for (int k = 0; k < 4; k++) {
        acc[2 * k]     += __builtin_bit_cast(float, wd[k] << 16);
        acc[2 * k + 1] += __builtin_bit_cast(float, wd[k] & 0xFFFF0000u);
      }
    }
  }
  short8 outv;
#pragma unroll
  for (int k = 0; k < 8; k++) outv[k] = f2s(acc[k]);
  *(short8*)((short*)A2 + (size_t)qrel * 2304 + l0) = outv;
}

// ---------------- stage 4: PV GEMM  out[o,q] = 0.25 * (Bb @ A2)[o,q] + input_l -------
// block: 128 q (M-dim) x 64 o (N-dim); C computed as C[m=q][n=o], transposed via LDS.
__global__ __launch_bounds__(256) void k_pv2(
    const bf16* __restrict__ A2, const bf16* __restrict__ Bb,
    const float* __restrict__ inl, float* __restrict__ out,
    int n, int q0base)
{
  __shared__ __align__(16) short As2[128 * 72];
  __shared__ __align__(16) short Bs2[64 * 72];
  __shared__ float Cst[4][64][20];
  int tid = threadIdx.x, lane = tid & 63, wv = tid >> 6;
  int quad = lane >> 4, m16 = lane & 15;
  int qb = blockIdx.x * 128;
  f32x4 acc[2][4];
#pragma unroll
  for (int i = 0; i < 2; i++)
#pragma unroll
    for (int t = 0; t < 4; t++) acc[i][t] = (f32x4){0.f, 0.f, 0.f, 0.f};

  const short* Ap = (const short*)A2 + (size_t)qb * 2304;
  const short* Bp = (const short*)Bb + (size_t)n * 64 * 2304;
  int arow = tid >> 1, acol = (tid & 1) * 32;
  int brow = tid >> 2, bcol = (tid & 3) * 16;

  for (int kk = 0; kk < 2304; kk += 64) {
    if (kk) __syncthreads();
#pragma unroll
    for (int v = 0; v < 4; v++)
      *(short8*)&As2[arow * 72 + acol + v * 8] = *(const short8*)&Ap[(size_t)arow * 2304 + kk + acol + v * 8];
#pragma unroll
    for (int v = 0; v < 2; v++)
      *(short8*)&Bs2[brow * 72 + bcol + v * 8] = *(const short8*)&Bp[(size_t)brow * 2304 + kk + bcol + v * 8];
    __syncthreads();
#pragma unroll
    for (int ks = 0; ks < 64; ks += 32) {
      short8 a0 = *(const short8*)&As2[(wv * 32 + m16) * 72 + ks + quad * 8];
      short8 a1 = *(const short8*)&As2[(wv * 32 + 16 + m16) * 72 + ks + quad * 8];
#pragma unroll
      for (int ni = 0; ni < 4; ni++) {
        short8 b = *(const short8*)&Bs2[(ni * 16 + m16) * 72 + ks + quad * 8];
        acc[0][ni] = __builtin_amdgcn_mfma_f32_16x16x32_bf16(a0, b, acc[0][ni], 0, 0, 0);
        acc[1][ni] = __builtin_amdgcn_mfma_f32_16x16x32_bf16(a1, b, acc[1][ni], 0, 0, 0);
      }
    }
  }

  // epilogue: transpose C[q][o] -> out[o][q] via per-wave LDS, fuse 0.25x + residual
#pragma unroll
  for (int half = 0; half < 2; half++) {
    __syncthreads();
#pragma unroll
    for (int ni = 0; ni < 4; ni++)
#pragma unroll
      for (int r = 0; r < 4; r++)
        Cst[wv][ni * 16 + m16][quad * 4 + r] = acc[half][ni][r];
    __syncthreads();
    int qg = q0base + qb + wv * 32 + half * 16 + (lane & 3) * 4;
#pragma unroll
    for (int rep = 0; rep < 4; rep++) {
      int o = rep * 16 + (lane >> 2);
      float4v c4 = *(float4v*)&Cst[wv][o][(lane & 3) * 4];
      size_t oid = ((size_t)(n * 64 + o)) * 9216 + qg;
      float4v r4 = *(const float4v*)&inl[oid];
      float4v y;
#pragma unroll
      for (int j = 0; j < 4; j++) y[j] = 0.25f * c4[j] + r4[j];
      *(float4v*)&out[oid] = y;
    }
  }
}

extern "C" void kernel_launch(void* const* d_in, const int* in_sizes, int n_in,
                              void* d_out, int out_size, void* d_ws, size_t ws_size,
                              hipStream_t stream)
{
  (void)in_sizes; (void)n_in; (void)out_size;
  const float* input_l = (const float*)d_in[0];
  const float* input_s = (const float*)d_in[1];
  const float* w_mlb = (const float*)d_in[2];
  const float* b_mlb = (const float*)d_in[3];
  const float* a_mlb = (const float*)d_in[4];
  const float* w_m   = (const float*)d_in[5];
  const float* b_m   = (const float*)d_in[6];
  const float* a_m   = (const float*)d_in[7];
  const float* w_asm = (const float*)d_in[8];
  const float* b_asm = (const float*)d_in[9];
  const float* a_asm = (const float*)d_in[10];
  float* out = (float*)d_out;

  char* base = (char*)d_ws;
  size_t off = 0;
  auto carve = [&](size_t bytes) -> char* {
    char* r = base + off;
    off += (bytes + 255) & ~(size_t)255;
    return r;
  };

  float* MBpad   = (float*)carve((size_t)4 * 32 * 98 * 98 * 4);
  float* REFpad  = (float*)carve((size_t)4 * 32 * 50 * 50 * 4);
  float* BASEpad = (float*)carve((size_t)4 * 64 * 50 * 50 * 4);
  bf16*  Kp      = (bf16*)carve((size_t)4 * 2304 * 288 * 2);
  bf16*  Xp      = (bf16*)carve((size_t)4 * 9216 * 288 * 2);
  bf16*  Bb      = (bf16*)carve((size_t)4 * 64 * 2304 * 2);
  float* statsM  = (float*)carve((size_t)9 * 9216 * 4);
  float* statsZ  = (float*)carve((size_t)9 * 9216 * 4);
  size_t fixedOff = off;

  // pick the coarsest query split whose attnT/A2 buffers fit ws
  auto need = [&](int qmax, int psplit) -> size_t {
    size_t a = ((size_t)qmax * 2304 * 2 + 255) & ~(size_t)255;
    size_t b2 = ((size_t)psplit * 2304 * 2 + 255) & ~(size_t)255;
    return fixedOff + a + b2;
  };
  int nsplit, qmax, psplit;
  if (need(9216, 9216) <= ws_size)      { nsplit = 1; qmax = 9216; psplit = 9216; }
  else if (need(5120, 4608) <= ws_size) { nsplit = 2; qmax = 5120; psplit = 4608; }
  else                                  { nsplit = 4; qmax = 2816; psplit = 2304; }

  bf16* attnT = (bf16*)carve((size_t)qmax * 2304 * 2);
  bf16* A2    = (bf16*)carve((size_t)psplit * 2304 * 2);

  // ---- prep (all samples) ----
  {
    int t1 = 4 * 32 * 98 * 98;
    k_conv1x1<<<dim3((t1 + 255) / 256), dim3(256), 0, stream>>>(input_l, w_mlb, b_mlb, a_mlb, MBpad, 32, 96, 96, t1);
    int t2 = 4 * 32 * 50 * 50;
    k_conv1x1<<<dim3((t2 + 255) / 256), dim3(256), 0, stream>>>(input_s, w_m, b_m, a_m, REFpad, 32, 48, 48, t2);
    int t3 = 4 * 64 * 50 * 50;
    k_conv1x1<<<dim3((t3 + 255) / 256), dim3(256), 0, stream>>>(input_s, w_asm, b_asm, a_asm, BASEpad, 64, 48, 48, t3);
    k_kp<<<dim3(2304), dim3(256), 0, stream>>>(REFpad, Kp);
    int t4 = 4 * 9216 * 288;
    k_xp<<<dim3(t4 / 256), dim3(256), 0, stream>>>(MBpad, Xp, t4);
    int t5 = 4 * 64 * 2304;
    k_baseT<<<dim3(t5 / 256), dim3(256), 0, stream>>>(BASEpad, Bb, t5);
  }

  // ---- attention per (sample, query band) ----
  for (int n = 0; n < 4; n++) {
    for (int s = 0; s < nsplit; s++) {
      int q0 = s * psplit;
      int qlo = q0 - 256; if (qlo < 0) qlo = 0;
      int qhi = q0 + psplit + 256; if (qhi > 9216) qhi = 9216;
      int qlen = qhi - qlo;  // multiple of 256 by construction
      k_qk<<<dim3(qlen / 128, 9), dim3(256), 0, stream>>>(Xp, Kp, attnT, statsM, statsZ, n, qlo);
      k_alpha2<<<dim3(qlen), dim3(256), 0, stream>>>(statsM, statsZ, attnT, qlo);
      k_a2<<<dim3(psplit * 288 / 256), dim3(256), 0, stream>>>(attnT, A2, q0, qlo);
      k_pv2<<<dim3(psplit / 128), dim3(256), 0, stream>>>(A2, Bb, input_l, out, n, q0);
    }
  }
}

// Round 5
// 687.328 us; speedup vs baseline: 1.4007x; 1.1237x over previous
//
#include <hip/hip_runtime.h>
#include <hip/hip_bf16.h>
#include <cstdint>
#include <cstddef>

typedef __hip_bfloat16 bf16;
using short8 = __attribute__((ext_vector_type(8))) short;
using f32x4  = __attribute__((ext_vector_type(4))) float;
using float4v = __attribute__((ext_vector_type(4))) float;
using uint4v  = __attribute__((ext_vector_type(4))) unsigned int;

__device__ __forceinline__ float s2f(short s) {
  unsigned u = ((unsigned)(unsigned short)s) << 16;
  return __builtin_bit_cast(float, u);
}
__device__ __forceinline__ short f2s(float f) {  // RNE f32->bf16
  unsigned u = __builtin_bit_cast(unsigned, f);
  u += 0x7fffu + ((u >> 16) & 1u);
  return (short)(u >> 16);
}
__device__ __forceinline__ float bclo(unsigned u) { return __builtin_bit_cast(float, u << 16); }
__device__ __forceinline__ float bchi(unsigned u) { return __builtin_bit_cast(float, u & 0xFFFF0000u); }

// ---------------- 1x1 conv + PReLU into zero-padded (+1 ring) f32 output ------------
__global__ __launch_bounds__(256) void k_conv1x1(
    const float* __restrict__ in, const float* __restrict__ w,
    const float* __restrict__ bias, const float* __restrict__ aprm,
    float* __restrict__ out, int Cout, int Hin, int Win, int total)
{
  int idx = blockIdx.x * 256 + threadIdx.x;
  if (idx >= total) return;
  int Wp = Win + 2, Hp = Hin + 2;
  int x = idx % Wp;
  int t = idx / Wp;
  int y = t % Hp; t /= Hp;
  int o = t % Cout; int n = t / Cout;
  if (x == 0 || x == Wp - 1 || y == 0 || y == Hp - 1) { out[idx] = 0.0f; return; }
  int cs = Hin * Win;
  const float* ip = in + (size_t)n * 64 * cs + (size_t)(y - 1) * Win + (x - 1);
  const float* wp = w + o * 64;
  float s = bias[o];
#pragma unroll 16
  for (int ci = 0; ci < 64; ci++)
    s += wp[ci] * ip[(size_t)ci * cs];
  float a = aprm[0];
  out[idx] = s >= 0.0f ? s : a * s;
}

// ---------------- key patches, L2-normalized, softmax scale 10 folded in ------------
__global__ __launch_bounds__(256) void k_kp(const float* __restrict__ refpad, bf16* __restrict__ Kp)
{
  int wid = blockIdx.x * 4 + (threadIdx.x >> 6);
  int lane = threadIdx.x & 63;
  if (wid >= 4 * 2304) return;
  int n = wid / 2304, l = wid % 2304, lh = l / 48, lw = l % 48;
  float v[5]; float ss = 0.f;
#pragma unroll
  for (int i = 0; i < 5; i++) {
    int k = lane + 64 * i; v[i] = 0.f;
    if (k < 288) {
      int c = k / 9, rr = (k % 9) / 3, sc = k % 3;
      v[i] = refpad[((size_t)(n * 32 + c) * 50 + lh + rr) * 50 + lw + sc];
      ss += v[i] * v[i];
    }
  }
#pragma unroll
  for (int off = 32; off; off >>= 1) ss += __shfl_xor(ss, off);
  float inv = 10.f / (sqrtf(ss) + 1e-4f);
#pragma unroll
  for (int i = 0; i < 5; i++) {
    int k = lane + 64 * i;
    if (k < 288) Kp[(size_t)wid * 288 + k] = __float2bfloat16(v[i] * inv);
  }
}

// ---------------- query patches Xp[n][p][288], bf16 ----------------
__global__ __launch_bounds__(256) void k_xp(const float* __restrict__ mbpad, bf16* __restrict__ Xp, int total)
{
  int idx = blockIdx.x * 256 + threadIdx.x;
  if (idx >= total) return;
  int k = idx % 288; int p = (idx / 288) % 9216; int n = idx / (288 * 9216);
  int c = k / 9, rr = (k % 9) / 3, sc = k % 3;
  int ph = p / 96, pw = p % 96;
  Xp[idx] = __float2bfloat16(mbpad[((size_t)(n * 32 + c) * 98 + ph + rr) * 98 + pw + sc]);
}

// ---------------- base value matrix Bb[n][o][l] (o-major, l contiguous), bf16 -------
__global__ __launch_bounds__(256) void k_baseT(const float* __restrict__ basepad, bf16* __restrict__ Bb, int total)
{
  int idx = blockIdx.x * 256 + threadIdx.x;
  if (idx >= total) return;
  int l = idx % 2304; int o = (idx / 2304) % 64; int n = idx / (2304 * 64);
  int lh = l / 48, lw = l % 48;
  Bb[idx] = __float2bfloat16(basepad[((size_t)(n * 64 + o) * 50 + lh + 1) * 50 + lw + 1]);
}

// ---------------- stage 1: QK tile GEMM + chunk-local softmax, writes P~ ------------
// block: 128 q x 256 l; 4 waves, each 32 q. A and B frags direct from L2-hot global
// (no K-loop barriers at all). LDS only for the coalesced P~ output staging.
__global__ __launch_bounds__(256, 2) void k_qk(
    const bf16* __restrict__ Xp, const bf16* __restrict__ Kp,
    bf16* __restrict__ attnT, float* __restrict__ statsM, float* __restrict__ statsZ,
    int nbase, int qlo, size_t attStride)
{
  __shared__ __align__(16) short Ps[64 * 264];
  int z = blockIdx.z;
  int n = nbase + z;
  int tid = threadIdx.x;
  int lane = tid & 63, wv = tid >> 6;
  int quad = lane >> 4, m16 = lane & 15;
  int q0 = qlo + blockIdx.x * 128;
  int l0 = blockIdx.y * 256;
  short* attZ = (short*)attnT + (size_t)z * attStride;
  float* sM = statsM + (size_t)z * 9 * 9216;
  float* sZ = statsZ + (size_t)z * 9 * 9216;

  f32x4 acc[2][16];
#pragma unroll
  for (int mi = 0; mi < 2; mi++)
#pragma unroll
    for (int t = 0; t < 16; t++) acc[mi][t] = (f32x4){0.f, 0.f, 0.f, 0.f};

  const short* Xrow = (const short*)Xp + ((size_t)n * 9216 + q0 + wv * 32 + m16) * 288;
  const short* Krow = (const short*)Kp + ((size_t)n * 2304 + l0 + m16) * 288;

  for (int kk = 0; kk < 288; kk += 32) {
    short8 a0 = *(const short8*)&Xrow[kk + quad * 8];
    short8 a1 = *(const short8*)&Xrow[16 * 288 + kk + quad * 8];
#pragma unroll
    for (int t = 0; t < 16; t++) {
      short8 b = *(const short8*)&Krow[(size_t)t * 16 * 288 + kk + quad * 8];
      acc[0][t] = __builtin_amdgcn_mfma_f32_16x16x32_bf16(a0, b, acc[0][t], 0, 0, 0);
      acc[1][t] = __builtin_amdgcn_mfma_f32_16x16x32_bf16(a1, b, acc[1][t], 0, 0, 0);
    }
  }

  // chunk-local softmax stats (row = q, reduce over cols = m16 lanes)
  float mrow[2][4], zrow[2][4];
#pragma unroll
  for (int mi = 0; mi < 2; mi++)
#pragma unroll
    for (int r = 0; r < 4; r++) mrow[mi][r] = -3.0e38f;
#pragma unroll
  for (int mi = 0; mi < 2; mi++)
#pragma unroll
    for (int t = 0; t < 16; t++)
#pragma unroll
      for (int r = 0; r < 4; r++) mrow[mi][r] = fmaxf(mrow[mi][r], acc[mi][t][r]);
#pragma unroll
  for (int off = 1; off < 16; off <<= 1)
#pragma unroll
    for (int mi = 0; mi < 2; mi++)
#pragma unroll
      for (int r = 0; r < 4; r++) mrow[mi][r] = fmaxf(mrow[mi][r], __shfl_xor(mrow[mi][r], off));
#pragma unroll
  for (int mi = 0; mi < 2; mi++)
#pragma unroll
    for (int r = 0; r < 4; r++) zrow[mi][r] = 0.f;
#pragma unroll
  for (int mi = 0; mi < 2; mi++)
#pragma unroll
    for (int t = 0; t < 16; t++)
#pragma unroll
      for (int r = 0; r < 4; r++) {
        float e = __expf(acc[mi][t][r] - mrow[mi][r]);
        acc[mi][t][r] = e;
        zrow[mi][r] += e;
      }
#pragma unroll
  for (int off = 1; off < 16; off <<= 1)
#pragma unroll
    for (int mi = 0; mi < 2; mi++)
#pragma unroll
      for (int r = 0; r < 4; r++) zrow[mi][r] += __shfl_xor(zrow[mi][r], off);
  if (m16 == 0) {
#pragma unroll
    for (int mi = 0; mi < 2; mi++)
#pragma unroll
      for (int r = 0; r < 4; r++) {
        int qq = q0 + wv * 32 + mi * 16 + quad * 4 + r;
        sM[blockIdx.y * 9216 + qq] = mrow[mi][r];
        sZ[blockIdx.y * 9216 + qq] = zrow[mi][r];
      }
  }

  // write P~ in two 64-row halves through LDS (coalesced global stores)
#pragma unroll
  for (int h = 0; h < 2; h++) {
    __syncthreads();
    if ((wv >> 1) == h) {
#pragma unroll
      for (int mi = 0; mi < 2; mi++)
#pragma unroll
        for (int t = 0; t < 16; t++)
#pragma unroll
          for (int r = 0; r < 4; r++)
            Ps[((wv & 1) * 32 + mi * 16 + quad * 4 + r) * 264 + t * 16 + m16] = f2s(acc[mi][t][r]);
    }
    __syncthreads();
    int row = tid >> 2, part = tid & 3;
    short* dst = attZ + (size_t)(q0 - qlo + h * 64 + row) * 2304 + l0 + part * 64;
    const short* sp = &Ps[row * 264 + part * 64];
#pragma unroll
    for (int v = 0; v < 8; v++)
      *(short8*)&dst[v * 8] = *(const short8*)&sp[v * 8];
  }
}

// ---------------- stage 2: combine chunk stats -> alpha[z][c][q] ----------------
__global__ __launch_bounds__(256) void k_alpha(
    const float* __restrict__ statsM, const float* __restrict__ statsZ,
    float* __restrict__ alpha, int qlo, int qlen)
{
  int i = blockIdx.x * 256 + threadIdx.x;
  if (i >= qlen) return;
  int z = blockIdx.z;
  int q = qlo + i;
  const float* sM = statsM + (size_t)z * 9 * 9216;
  const float* sZ = statsZ + (size_t)z * 9 * 9216;
  float* al = alpha + (size_t)z * 9 * 9216;
  float M = -3.0e38f;
#pragma unroll
  for (int c = 0; c < 9; c++) M = fmaxf(M, sM[c * 9216 + q]);
  float Z = 0.f;
#pragma unroll
  for (int c = 0; c < 9; c++) Z += sZ[c * 9216 + q] * __expf(sM[c * 9216 + q] - M);
  float invZ = 1.f / Z;
#pragma unroll
  for (int c = 0; c < 9; c++) al[c * 9216 + q] = __expf(sM[c * 9216 + q] - M) * invZ;
}

// ---- stage 3: 9-point diagonal stencil with fused alpha --------------------------
// A2[l,q] = sum_d P~[l+dl, q+dq] * alpha[c(l+dl)][q+dq]
// thread = 8 consecutive l of one q row; aligned uint4 loads + funnel shifts.
// blockIdx.x swizzled so each XCD gets a contiguous q band (L2 locality).
__global__ __launch_bounds__(256) void k_a2(
    const bf16* __restrict__ attnT, const float* __restrict__ alpha,
    bf16* __restrict__ A2, int q0, int qlo, size_t attStride, size_t a2Stride)
{
  int bpx = gridDim.x >> 3;
  int nb = (blockIdx.x & 7) * bpx + (blockIdx.x >> 3);
  int g = nb * 256 + threadIdx.x;
  int z = blockIdx.z;
  const short* att = (const short*)attnT + (size_t)z * attStride;
  const float* alq = alpha + (size_t)z * 9 * 9216;
  short* a2 = (short*)A2 + (size_t)z * a2Stride;
  int qrel = g / 288;                 // 288 groups of 8 per q row
  int j = g - qrel * 288;
  int l0 = j * 8;
  int q = q0 + qrel;
  int h = q / 96, w = q - h * 96;
  int lh = l0 / 48, lw0 = l0 - lh * 48;
  float acc[8];
#pragma unroll
  for (int k = 0; k < 8; k++) acc[k] = 0.f;
#pragma unroll
  for (int di = -1; di <= 1; di++) {
    int hh = h + di, lhh = lh + di;
    if (hh < 0 || hh >= 96 || lhh < 0 || lhh >= 48) continue;
    int lb = l0 + 48 * di;            // multiple of 8 -> 16B aligned
    int qv = q + 96 * di;
    const short* r0 = att + (size_t)(qv - qlo) * 2304;
    int c0 = lb >> 8;
    const float* alc = alq + c0 * 9216;
    { // dj = 0 (never l-masked: lw in [0,47]; group never crosses 256-chunk)
      float a = alc[qv];
      uint4v V = *(const uint4v*)(r0 + lb);
#pragma unroll
      for (int k = 0; k < 4; k++) {
        acc[2 * k]     += bclo(V[k]) * a;
        acc[2 * k + 1] += bchi(V[k]) * a;
      }
    }
    if (w > 0) { // dj = -1: window shorts [lb-1 .. lb+6]; elem0 may be chunk c0-1
      const short* rm = r0 - 2304;
      int qp = qv - 1;
      float am = alc[qp];
      float a0 = ((lb & 255) == 0 && c0 > 0) ? alq[(c0 - 1) * 9216 + qp] : am;
      uint4v V = *(const uint4v*)(rm + lb);
      unsigned P = *(const unsigned*)(rm + lb - 2);
      unsigned w0 = (P >> 16) | (V[0] << 16);
      if (lw0 == 0) w0 &= 0xFFFF0000u;     // element 0 would wrap to prev lh row
      unsigned wd1 = (V[0] >> 16) | (V[1] << 16);
      unsigned wd2 = (V[1] >> 16) | (V[2] << 16);
      unsigned wd3 = (V[2] >> 16) | (V[3] << 16);
      acc[0] += bclo(w0) * a0;  acc[1] += bchi(w0) * am;
      acc[2] += bclo(wd1) * am; acc[3] += bchi(wd1) * am;
      acc[4] += bclo(wd2) * am; acc[5] += bchi(wd2) * am;
      acc[6] += bclo(wd3) * am; acc[7] += bchi(wd3) * am;
    }
    if (w < 95) { // dj = +1: window shorts [lb+1 .. lb+8]; elem7 may be chunk c0+1
      const short* rp = r0 + 2304;
      int qp = qv + 1;
      float am = alc[qp];
      float a7 = ((lb & 255) == 248 && c0 < 8) ? alq[(c0 + 1) * 9216 + qp] : am;
      uint4v V = *(const uint4v*)(rp + lb);
      unsigned N = *(const unsigned*)(rp + lb + 8);
      unsigned w3 = (V[3] >> 16) | (N << 16);
      if (lw0 == 40) w3 &= 0x0000FFFFu;    // element 7 would wrap to next lh row
      unsigned wd0 = (V[0] >> 16) | (V[1] << 16);
      unsigned wd1 = (V[1] >> 16) | (V[2] << 16);
      unsigned wd2 = (V[2] >> 16) | (V[3] << 16);
      acc[0] += bclo(wd0) * am; acc[1] += bchi(wd0) * am;
      acc[2] += bclo(wd1) * am; acc[3] += bchi(wd1) * am;
      acc[4] += bclo(wd2) * am; acc[5] += bchi(wd2) * am;
      acc[6] += bclo(w3) * am;  acc[7] += bchi(w3) * a7;
    }
  }
  short8 outv;
#pragma unroll
  for (int k = 0; k < 8; k++) outv[k] = f2s(acc[k]);
  *(short8*)(a2 + (size_t)qrel * 2304 + l0) = outv;
}

// ---------------- stage 4: PV GEMM  out[o,q] = 0.25 * (Bb @ A2)[o,q] + input_l -------
// block: 128 q (M-dim) x 64 o (N-dim); C computed as C[m=q][n=o], transposed via LDS.
__global__ __launch_bounds__(256) void k_pv2(
    const bf16* __restrict__ A2, const bf16* __restrict__ Bb,
    const float* __restrict__ inl, float* __restrict__ out,
    int nbase, int q0base, size_t a2Stride)
{
  __shared__ __align__(16) short As2[128 * 72];
  __shared__ __align__(16) short Bs2[64 * 72];
  __shared__ float Cst[4][64][20];
  int z = blockIdx.z;
  int n = nbase + z;
  int tid = threadIdx.x, lane = tid & 63, wv = tid >> 6;
  int quad = lane >> 4, m16 = lane & 15;
  int qb = blockIdx.x * 128;
  f32x4 acc[2][4];
#pragma unroll
  for (int i = 0; i < 2; i++)
#pragma unroll
    for (int t = 0; t < 4; t++) acc[i][t] = (f32x4){0.f, 0.f, 0.f, 0.f};

  const short* Ap = (const short*)A2 + (size_t)z * a2Stride + (size_t)qb * 2304;
  const short* Bp = (const short*)Bb + (size_t)n * 64 * 2304;
  int arow = tid >> 1, acol = (tid & 1) * 32;
  int brow = tid >> 2, bcol = (tid & 3) * 16;

  for (int kk = 0; kk < 2304; kk += 64) {
    if (kk) __syncthreads();
#pragma unroll
    for (int v = 0; v < 4; v++)
      *(short8*)&As2[arow * 72 + acol + v * 8] = *(const short8*)&Ap[(size_t)arow * 2304 + kk + acol + v * 8];
#pragma unroll
    for (int v = 0; v < 2; v++)
      *(short8*)&Bs2[brow * 72 + bcol + v * 8] = *(const short8*)&Bp[(size_t)brow * 2304 + kk + bcol + v * 8];
    __syncthreads();
#pragma unroll
    for (int ks = 0; ks < 64; ks += 32) {
      short8 a0 = *(const short8*)&As2[(wv * 32 + m16) * 72 + ks + quad * 8];
      short8 a1 = *(const short8*)&As2[(wv * 32 + 16 + m16) * 72 + ks + quad * 8];
#pragma unroll
      for (int ni = 0; ni < 4; ni++) {
        short8 b = *(const short8*)&Bs2[(ni * 16 + m16) * 72 + ks + quad * 8];
        acc[0][ni] = __builtin_amdgcn_mfma_f32_16x16x32_bf16(a0, b, acc[0][ni], 0, 0, 0);
        acc[1][ni] = __builtin_amdgcn_mfma_f32_16x16x32_bf16(a1, b, acc[1][ni], 0, 0, 0);
      }
    }
  }

  // epilogue: transpose C[q][o] -> out[o][q] via per-wave LDS, fuse 0.25x + residual
#pragma unroll
  for (int half = 0; half < 2; half++) {
    __syncthreads();
#pragma unroll
    for (int ni = 0; ni < 4; ni++)
#pragma unroll
      for (int r = 0; r < 4; r++)
        Cst[wv][ni * 16 + m16][quad * 4 + r] = acc[half][ni][r];
    __syncthreads();
    int qg = q0base + qb + wv * 32 + half * 16 + (lane & 3) * 4;
#pragma unroll
    for (int rep = 0; rep < 4; rep++) {
      int o = rep * 16 + (lane >> 2);
      float4v c4 = *(float4v*)&Cst[wv][o][(lane & 3) * 4];
      size_t oid = ((size_t)(n * 64 + o)) * 9216 + qg;
      float4v r4 = *(const float4v*)&inl[oid];
      float4v y;
#pragma unroll
      for (int j = 0; j < 4; j++) y[j] = 0.25f * c4[j] + r4[j];
      *(float4v*)&out[oid] = y;
    }
  }
}

extern "C" void kernel_launch(void* const* d_in, const int* in_sizes, int n_in,
                              void* d_out, int out_size, void* d_ws, size_t ws_size,
                              hipStream_t stream)
{
  (void)in_sizes; (void)n_in; (void)out_size;
  const float* input_l = (const float*)d_in[0];
  const float* input_s = (const float*)d_in[1];
  const float* w_mlb = (const float*)d_in[2];
  const float* b_mlb = (const float*)d_in[3];
  const float* a_mlb = (const float*)d_in[4];
  const float* w_m   = (const float*)d_in[5];
  const float* b_m   = (const float*)d_in[6];
  const float* a_m   = (const float*)d_in[7];
  const float* w_asm = (const float*)d_in[8];
  const float* b_asm = (const float*)d_in[9];
  const float* a_asm = (const float*)d_in[10];
  float* out = (float*)d_out;

  char* base = (char*)d_ws;
  size_t off = 0;
  auto carve = [&](size_t bytes) -> char* {
    char* r = base + off;
    off += (bytes + 255) & ~(size_t)255;
    return r;
  };

  float* MBpad   = (float*)carve((size_t)4 * 32 * 98 * 98 * 4);
  float* REFpad  = (float*)carve((size_t)4 * 32 * 50 * 50 * 4);
  float* BASEpad = (float*)carve((size_t)4 * 64 * 50 * 50 * 4);
  bf16*  Kp      = (bf16*)carve((size_t)4 * 2304 * 288 * 2);
  bf16*  Xp      = (bf16*)carve((size_t)4 * 9216 * 288 * 2);
  bf16*  Bb      = (bf16*)carve((size_t)4 * 64 * 2304 * 2);
  float* statsM  = (float*)carve((size_t)4 * 9 * 9216 * 4);
  float* statsZ  = (float*)carve((size_t)4 * 9 * 9216 * 4);
  float* alpha   = (float*)carve((size_t)4 * 9 * 9216 * 4);
  size_t fixedOff = off;

  auto need = [&](int qmax, int psplit, int zc) -> size_t {
    size_t a = (((size_t)qmax * 2304 * 2 + 255) & ~(size_t)255) * zc;
    size_t b2 = (((size_t)psplit * 2304 * 2 + 255) & ~(size_t)255) * zc;
    return fixedOff + a + b2;
  };

  // ---- prep (all samples) ----
  {
    int t1 = 4 * 32 * 98 * 98;
    k_conv1x1<<<dim3((t1 + 255) / 256), dim3(256), 0, stream>>>(input_l, w_mlb, b_mlb, a_mlb, MBpad, 32, 96, 96, t1);
    int t2 = 4 * 32 * 50 * 50;
    k_conv1x1<<<dim3((t2 + 255) / 256), dim3(256), 0, stream>>>(input_s, w_m, b_m, a_m, REFpad, 32, 48, 48, t2);
    int t3 = 4 * 64 * 50 * 50;
    k_conv1x1<<<dim3((t3 + 255) / 256), dim3(256), 0, stream>>>(input_s, w_asm, b_asm, a_asm, BASEpad, 64, 48, 48, t3);
    k_kp<<<dim3(2304), dim3(256), 0, stream>>>(REFpad, Kp);
    int t4 = 4 * 9216 * 288;
    k_xp<<<dim3(t4 / 256), dim3(256), 0, stream>>>(MBpad, Xp, t4);
    int t5 = 4 * 64 * 2304;
    k_baseT<<<dim3(t5 / 256), dim3(256), 0, stream>>>(BASEpad, Bb, t5);
  }

  if (need(9216, 9216, 4) <= ws_size) {
    // ---- fully batched: all 4 samples in grid.z, one pass, 4 dispatches ----
    size_t attStride = (size_t)9216 * 2304;   // elements (shorts)
    bf16* attnT = (bf16*)carve((size_t)4 * attStride * 2);
    bf16* A2    = (bf16*)carve((size_t)4 * attStride * 2);
    k_qk<<<dim3(72, 9, 4), dim3(256), 0, stream>>>(Xp, Kp, attnT, statsM, statsZ, 0, 0, attStride);
    k_alpha<<<dim3(36, 1, 4), dim3(256), 0, stream>>>(statsM, statsZ, alpha, 0, 9216);
    k_a2<<<dim3(10368, 1, 4), dim3(256), 0, stream>>>(attnT, alpha, A2, 0, 0, attStride, attStride);
    k_pv2<<<dim3(72, 1, 4), dim3(256), 0, stream>>>(A2, Bb, input_l, out, 0, 0, attStride);
  } else {
    // ---- per-sample banded fallback ----
    int nsplit, qmax, psplit;
    if (need(9216, 9216, 1) <= ws_size)      { nsplit = 1; qmax = 9216; psplit = 9216; }
    else if (need(5120, 4608, 1) <= ws_size) { nsplit = 2; qmax = 5120; psplit = 4608; }
    else                                     { nsplit = 4; qmax = 2816; psplit = 2304; }
    bf16* attnT = (bf16*)carve((size_t)qmax * 2304 * 2);
    bf16* A2    = (bf16*)carve((size_t)psplit * 2304 * 2);
    for (int n = 0; n < 4; n++) {
      for (int s = 0; s < nsplit; s++) {
        int q0 = s * psplit;
        int qlo = q0 - 256; if (qlo < 0) qlo = 0;
        int qhi = q0 + psplit + 256; if (qhi > 9216) qhi = 9216;
        int qlen = qhi - qlo;  // multiple of 256 by construction
        k_qk<<<dim3(qlen / 128, 9, 1), dim3(256), 0, stream>>>(Xp, Kp, attnT, statsM, statsZ, n, qlo, 0);
        k_alpha<<<dim3(qlen / 256, 1, 1), dim3(256), 0, stream>>>(statsM, statsZ, alpha, qlo, qlen);
        k_a2<<<dim3(psplit * 288 / 256, 1, 1), dim3(256), 0, stream>>>(attnT, alpha, A2, q0, qlo, 0, 0);
        k_pv2<<<dim3(psplit / 128, 1, 1), dim3(256), 0, stream>>>(A2, Bb, input_l, out, n, q0, 0);
      }
    }
  }
}

// Round 6
// 618.409 us; speedup vs baseline: 1.5569x; 1.1114x over previous
//
#include <hip/hip_runtime.h>
#include <hip/hip_bf16.h>
#include <cstdint>
#include <cstddef>

typedef __hip_bfloat16 bf16;
using short8 = __attribute__((ext_vector_type(8))) short;
using f32x4  = __attribute__((ext_vector_type(4))) float;
using float4v = __attribute__((ext_vector_type(4))) float;
using uint4v  = __attribute__((ext_vector_type(4))) unsigned int;

__device__ __forceinline__ float s2f(short s) {
  unsigned u = ((unsigned)(unsigned short)s) << 16;
  return __builtin_bit_cast(float, u);
}
__device__ __forceinline__ short f2s(float f) {  // RNE f32->bf16
  unsigned u = __builtin_bit_cast(unsigned, f);
  u += 0x7fffu + ((u >> 16) & 1u);
  return (short)(u >> 16);
}
__device__ __forceinline__ float bclo(unsigned u) { return __builtin_bit_cast(float, u << 16); }
__device__ __forceinline__ float bchi(unsigned u) { return __builtin_bit_cast(float, u & 0xFFFF0000u); }

// ---------------- 1x1 conv + PReLU into zero-padded (+1 ring) f32 output ------------
__global__ __launch_bounds__(256) void k_conv1x1(
    const float* __restrict__ in, const float* __restrict__ w,
    const float* __restrict__ bias, const float* __restrict__ aprm,
    float* __restrict__ out, int Cout, int Hin, int Win, int total)
{
  int idx = blockIdx.x * 256 + threadIdx.x;
  if (idx >= total) return;
  int Wp = Win + 2, Hp = Hin + 2;
  int x = idx % Wp;
  int t = idx / Wp;
  int y = t % Hp; t /= Hp;
  int o = t % Cout; int n = t / Cout;
  if (x == 0 || x == Wp - 1 || y == 0 || y == Hp - 1) { out[idx] = 0.0f; return; }
  int cs = Hin * Win;
  const float* ip = in + (size_t)n * 64 * cs + (size_t)(y - 1) * Win + (x - 1);
  const float* wp = w + o * 64;
  float s = bias[o];
#pragma unroll 16
  for (int ci = 0; ci < 64; ci++)
    s += wp[ci] * ip[(size_t)ci * cs];
  float a = aprm[0];
  out[idx] = s >= 0.0f ? s : a * s;
}

// ---------------- key patches, L2-normalized, softmax scale 10 folded in ------------
__global__ __launch_bounds__(256) void k_kp(const float* __restrict__ refpad, bf16* __restrict__ Kp)
{
  int wid = blockIdx.x * 4 + (threadIdx.x >> 6);
  int lane = threadIdx.x & 63;
  if (wid >= 4 * 2304) return;
  int n = wid / 2304, l = wid % 2304, lh = l / 48, lw = l % 48;
  float v[5]; float ss = 0.f;
#pragma unroll
  for (int i = 0; i < 5; i++) {
    int k = lane + 64 * i; v[i] = 0.f;
    if (k < 288) {
      int c = k / 9, rr = (k % 9) / 3, sc = k % 3;
      v[i] = refpad[((size_t)(n * 32 + c) * 50 + lh + rr) * 50 + lw + sc];
      ss += v[i] * v[i];
    }
  }
#pragma unroll
  for (int off = 32; off; off >>= 1) ss += __shfl_xor(ss, off);
  float inv = 10.f / (sqrtf(ss) + 1e-4f);
#pragma unroll
  for (int i = 0; i < 5; i++) {
    int k = lane + 64 * i;
    if (k < 288) Kp[(size_t)wid * 288 + k] = __float2bfloat16(v[i] * inv);
  }
}

// ---------------- query patches Xp[n][p][288], bf16 ----------------
__global__ __launch_bounds__(256) void k_xp(const float* __restrict__ mbpad, bf16* __restrict__ Xp, int total)
{
  int idx = blockIdx.x * 256 + threadIdx.x;
  if (idx >= total) return;
  int k = idx % 288; int p = (idx / 288) % 9216; int n = idx / (288 * 9216);
  int c = k / 9, rr = (k % 9) / 3, sc = k % 3;
  int ph = p / 96, pw = p % 96;
  Xp[idx] = __float2bfloat16(mbpad[((size_t)(n * 32 + c) * 98 + ph + rr) * 98 + pw + sc]);
}

// ---------------- base value matrix Bb[n][o][l] (o-major, l contiguous), bf16 -------
__global__ __launch_bounds__(256) void k_baseT(const float* __restrict__ basepad, bf16* __restrict__ Bb, int total)
{
  int idx = blockIdx.x * 256 + threadIdx.x;
  if (idx >= total) return;
  int l = idx % 2304; int o = (idx / 2304) % 64; int n = idx / (2304 * 64);
  int lh = l / 48, lw = l % 48;
  Bb[idx] = __float2bfloat16(basepad[((size_t)(n * 64 + o) * 50 + lh + 1) * 50 + lw + 1]);
}

// ---------------- stage 1: QK tile GEMM + chunk-local softmax, writes P~ ------------
// block: 64q x 256l, 2x2 waves of 32q x 128l (acc = 64 VGPR). Ks LDS-staged with
// XOR swizzle (<=2-way banks). Cross-wave stat combine. XCD-swizzled q bands.
__global__ __launch_bounds__(256) void k_qk(
    const bf16* __restrict__ Xp, const bf16* __restrict__ Kp,
    bf16* __restrict__ attnT, float* __restrict__ statsM, float* __restrict__ statsZ,
    int n, int qlo)
{
  __shared__ __align__(16) short KsPs[64 * 264];   // union: Ks 256x40 / Ps 64x264
  __shared__ float Sm[2][2][32];
  __shared__ float Sz[2][2][32];
  int tid = threadIdx.x, lane = tid & 63, wv = tid >> 6;
  int quad = lane >> 4, m16 = lane & 15;
  int wr = wv >> 1, wc = wv & 1;
  int bpx = gridDim.x >> 3;
  int bx = blockIdx.x;
  int nb = (bx < (bpx << 3)) ? ((bx & 7) * bpx + (bx >> 3)) : bx;
  int q0 = qlo + nb * 64;
  int l0 = blockIdx.y * 256;

  f32x4 acc[2][8];
#pragma unroll
  for (int mi = 0; mi < 2; mi++)
#pragma unroll
    for (int t = 0; t < 8; t++) acc[mi][t] = (f32x4){0.f, 0.f, 0.f, 0.f};

  const short* Xrow = (const short*)Xp + ((size_t)n * 9216 + q0 + wr * 32 + m16) * 288;
  const short* Ksrc = (const short*)Kp + ((size_t)n * 2304 + l0) * 288;
  int srow4 = tid >> 2, spart = tid & 3;

  for (int kk = 0; kk < 288; kk += 32) {
    if (kk) __syncthreads();
#pragma unroll
    for (int p = 0; p < 4; p++) {
      int row = srow4 + p * 64;
      short8 v = *(const short8*)&Ksrc[(size_t)row * 288 + kk + spart * 8];
      *(short8*)&KsPs[row * 40 + ((spart ^ ((row >> 3) & 3)) << 3)] = v;
    }
    __syncthreads();
    short8 a0 = *(const short8*)&Xrow[kk + quad * 8];
    short8 a1 = *(const short8*)&Xrow[16 * 288 + kk + quad * 8];
#pragma unroll
    for (int t = 0; t < 8; t++) {
      int R = wc * 128 + t * 16 + m16;
      short8 b = *(const short8*)&KsPs[R * 40 + ((quad ^ ((R >> 3) & 3)) << 3)];
      acc[0][t] = __builtin_amdgcn_mfma_f32_16x16x32_bf16(a0, b, acc[0][t], 0, 0, 0);
      acc[1][t] = __builtin_amdgcn_mfma_f32_16x16x32_bf16(a1, b, acc[1][t], 0, 0, 0);
    }
  }

  // local stats over this wave's 128 l
  float mloc[2][4], zloc[2][4], scale[2][4];
#pragma unroll
  for (int mi = 0; mi < 2; mi++)
#pragma unroll
    for (int r = 0; r < 4; r++) mloc[mi][r] = -3.0e38f;
#pragma unroll
  for (int mi = 0; mi < 2; mi++)
#pragma unroll
    for (int t = 0; t < 8; t++)
#pragma unroll
      for (int r = 0; r < 4; r++) mloc[mi][r] = fmaxf(mloc[mi][r], acc[mi][t][r]);
#pragma unroll
  for (int off = 1; off < 16; off <<= 1)
#pragma unroll
    for (int mi = 0; mi < 2; mi++)
#pragma unroll
      for (int r = 0; r < 4; r++) mloc[mi][r] = fmaxf(mloc[mi][r], __shfl_xor(mloc[mi][r], off));
#pragma unroll
  for (int mi = 0; mi < 2; mi++)
#pragma unroll
    for (int r = 0; r < 4; r++) zloc[mi][r] = 0.f;
#pragma unroll
  for (int mi = 0; mi < 2; mi++)
#pragma unroll
    for (int t = 0; t < 8; t++)
#pragma unroll
      for (int r = 0; r < 4; r++) {
        float e = __expf(acc[mi][t][r] - mloc[mi][r]);
        acc[mi][t][r] = e;
        zloc[mi][r] += e;
      }
#pragma unroll
  for (int off = 1; off < 16; off <<= 1)
#pragma unroll
    for (int mi = 0; mi < 2; mi++)
#pragma unroll
      for (int r = 0; r < 4; r++) zloc[mi][r] += __shfl_xor(zloc[mi][r], off);
  if (m16 == 0) {
#pragma unroll
    for (int mi = 0; mi < 2; mi++)
#pragma unroll
      for (int r = 0; r < 4; r++) {
        int qi = mi * 16 + quad * 4 + r;
        Sm[wc][wr][qi] = mloc[mi][r];
        Sz[wc][wr][qi] = zloc[mi][r];
      }
  }
  __syncthreads();   // also guards Ks reuse as Ps below
#pragma unroll
  for (int mi = 0; mi < 2; mi++)
#pragma unroll
    for (int r = 0; r < 4; r++) {
      int qi = mi * 16 + quad * 4 + r;
      float mo = Sm[wc ^ 1][wr][qi];
      float zo = Sz[wc ^ 1][wr][qi];
      float mc = fmaxf(mloc[mi][r], mo);
      float sc = __expf(mloc[mi][r] - mc);
      scale[mi][r] = sc;
      if (m16 == 0 && wc == 0) {
        float zc = zloc[mi][r] * sc + zo * __expf(mo - mc);
        int qq = q0 + wr * 32 + qi;
        statsM[blockIdx.y * 9216 + qq] = mc;
        statsZ[blockIdx.y * 9216 + qq] = zc;
      }
    }
  // write P~ tile through LDS (coalesced global stores)
#pragma unroll
  for (int mi = 0; mi < 2; mi++)
#pragma unroll
    for (int t = 0; t < 8; t++)
#pragma unroll
      for (int r = 0; r < 4; r++)
        KsPs[(wr * 32 + mi * 16 + quad * 4 + r) * 264 + wc * 128 + t * 16 + m16] =
            f2s(acc[mi][t][r] * scale[mi][r]);
  __syncthreads();
  {
    int row = tid >> 2, part = tid & 3;
    short* dst = (short*)attnT + (size_t)(q0 - qlo + row) * 2304 + l0 + part * 64;
    const short* sp = &KsPs[row * 264 + part * 64];
#pragma unroll
    for (int v = 0; v < 8; v++)
      *(short8*)&dst[v * 8] = *(const short8*)&sp[v * 8];
  }
}

// ---------------- stage 2: combine chunk stats -> alpha[c][q] ----------------
__global__ __launch_bounds__(256) void k_alpha(
    const float* __restrict__ statsM, const float* __restrict__ statsZ,
    float* __restrict__ alpha, int qlo, int qlen)
{
  int i = blockIdx.x * 256 + threadIdx.x;
  if (i >= qlen) return;
  int q = qlo + i;
  float M = -3.0e38f;
#pragma unroll
  for (int c = 0; c < 9; c++) M = fmaxf(M, statsM[c * 9216 + q]);
  float Z = 0.f;
#pragma unroll
  for (int c = 0; c < 9; c++) Z += statsZ[c * 9216 + q] * __expf(statsM[c * 9216 + q] - M);
  float invZ = 1.f / Z;
#pragma unroll
  for (int c = 0; c < 9; c++) alpha[c * 9216 + q] = __expf(statsM[c * 9216 + q] - M) * invZ;
}

// ---- stage 3: 9-point diagonal stencil with fused alpha --------------------------
// A2[l,q] = sum_d P~[l+dl, q+dq] * alpha[c(l+dl)][q+dq]
// thread = 8 consecutive l of one q row; aligned uint4 loads + funnel shifts.
// blockIdx.x swizzled so each XCD gets a contiguous q band (L2 locality).
__global__ __launch_bounds__(256) void k_a2(
    const bf16* __restrict__ attnT, const float* __restrict__ alpha,
    bf16* __restrict__ A2, int q0, int qlo)
{
  int bpx = gridDim.x >> 3;
  int nb = (blockIdx.x & 7) * bpx + (blockIdx.x >> 3);
  int g = nb * 256 + threadIdx.x;
  const short* att = (const short*)attnT;
  short* a2 = (short*)A2;
  int qrel = g / 288;                 // 288 groups of 8 per q row
  int j = g - qrel * 288;
  int l0 = j * 8;
  int q = q0 + qrel;
  int h = q / 96, w = q - h * 96;
  int lh = l0 / 48, lw0 = l0 - lh * 48;
  float acc[8];
#pragma unroll
  for (int k = 0; k < 8; k++) acc[k] = 0.f;
#pragma unroll
  for (int di = -1; di <= 1; di++) {
    int hh = h + di, lhh = lh + di;
    if (hh < 0 || hh >= 96 || lhh < 0 || lhh >= 48) continue;
    int lb = l0 + 48 * di;            // multiple of 8 -> 16B aligned
    int qv = q + 96 * di;
    const short* r0 = att + (size_t)(qv - qlo) * 2304;
    int c0 = lb >> 8;
    const float* alc = alpha + c0 * 9216;
    { // dj = 0
      float a = alc[qv];
      uint4v V = *(const uint4v*)(r0 + lb);
#pragma unroll
      for (int k = 0; k < 4; k++) {
        acc[2 * k]     += bclo(V[k]) * a;
        acc[2 * k + 1] += bchi(V[k]) * a;
      }
    }
    if (w > 0) { // dj = -1: window shorts [lb-1 .. lb+6]; elem0 may be chunk c0-1
      const short* rm = r0 - 2304;
      int qp = qv - 1;
      float am = alc[qp];
      float a0 = ((lb & 255) == 0 && c0 > 0) ? alpha[(c0 - 1) * 9216 + qp] : am;
      uint4v V = *(const uint4v*)(rm + lb);
      unsigned P = *(const unsigned*)(rm + lb - 2);
      unsigned w0 = (P >> 16) | (V[0] << 16);
      if (lw0 == 0) w0 &= 0xFFFF0000u;
      unsigned wd1 = (V[0] >> 16) | (V[1] << 16);
      unsigned wd2 = (V[1] >> 16) | (V[2] << 16);
      unsigned wd3 = (V[2] >> 16) | (V[3] << 16);
      acc[0] += bclo(w0) * a0;  acc[1] += bchi(w0) * am;
      acc[2] += bclo(wd1) * am; acc[3] += bchi(wd1) * am;
      acc[4] += bclo(wd2) * am; acc[5] += bchi(wd2) * am;
      acc[6] += bclo(wd3) * am; acc[7] += bchi(wd3) * am;
    }
    if (w < 95) { // dj = +1: window shorts [lb+1 .. lb+8]; elem7 may be chunk c0+1
      const short* rp = r0 + 2304;
      int qp = qv + 1;
      float am = alc[qp];
      float a7 = ((lb & 255) == 248 && c0 < 8) ? alpha[(c0 + 1) * 9216 + qp] : am;
      uint4v V = *(const uint4v*)(rp + lb);
      unsigned N = *(const unsigned*)(rp + lb + 8);
      unsigned w3 = (V[3] >> 16) | (N << 16);
      if (lw0 == 40) w3 &= 0x0000FFFFu;
      unsigned wd0 = (V[0] >> 16) | (V[1] << 16);
      unsigned wd1 = (V[1] >> 16) | (V[2] << 16);
      unsigned wd2 = (V[2] >> 16) | (V[3] << 16);
      acc[0] += bclo(wd0) * am; acc[1] += bchi(wd0) * am;
      acc[2] += bclo(wd1) * am; acc[3] += bchi(wd1) * am;
      acc[4] += bclo(wd2) * am; acc[5] += bchi(wd2) * am;
      acc[6] += bclo(w3) * am;  acc[7] += bchi(w3) * a7;
    }
  }
  short8 outv;
#pragma unroll
  for (int k = 0; k < 8; k++) outv[k] = f2s(acc[k]);
  *(short8*)(a2 + (size_t)qrel * 2304 + l0) = outv;
}

// ---- stage 4: PV GEMM, in-block split-K ------------------------------------------
// block = 16q x 64o; 4 waves each own 576 of K=2304 (no barriers in k-loop),
// LDS reduction, fused 0.25*C + residual epilogue. A2 streamed exactly once.
__global__ __launch_bounds__(256) void k_pv3(
    const bf16* __restrict__ A2, const bf16* __restrict__ Bb,
    const float* __restrict__ inl, float* __restrict__ out,
    int n, int q0base)
{
  __shared__ float Cred[4][16][67];
  int tid = threadIdx.x, lane = tid & 63, wv = tid >> 6;
  int quad = lane >> 4, m16 = lane & 15;
  int qb = blockIdx.x * 16;
  int kbase = wv * 576;
  f32x4 acc[4];
#pragma unroll
  for (int t = 0; t < 4; t++) acc[t] = (f32x4){0.f, 0.f, 0.f, 0.f};

  const short* Ap = (const short*)A2 + (size_t)qb * 2304 + kbase;
  const short* Bp = (const short*)Bb + (size_t)n * 64 * 2304 + kbase;

#pragma unroll
  for (int it = 0; it < 9; it++) {
    int kw = it * 64;
#pragma unroll
    for (int ks = 0; ks < 64; ks += 32) {
      short8 a = *(const short8*)&Ap[(size_t)m16 * 2304 + kw + ks + quad * 8];
#pragma unroll
      for (int ni = 0; ni < 4; ni++) {
        short8 b = *(const short8*)&Bp[(size_t)(ni * 16 + m16) * 2304 + kw + ks + quad * 8];
        acc[ni] = __builtin_amdgcn_mfma_f32_16x16x32_bf16(a, b, acc[ni], 0, 0, 0);
      }
    }
  }
#pragma unroll
  for (int ni = 0; ni < 4; ni++)
#pragma unroll
    for (int r = 0; r < 4; r++)
      Cred[wv][quad * 4 + r][ni * 16 + m16] = acc[ni][r];
  __syncthreads();
  {
    int o = tid >> 2;                // 0..63
    int qg = (tid & 3) * 4;          // 0..12
    float4v s;
#pragma unroll
    for (int j = 0; j < 4; j++)
      s[j] = Cred[0][qg + j][o] + Cred[1][qg + j][o] + Cred[2][qg + j][o] + Cred[3][qg + j][o];
    size_t oid = ((size_t)(n * 64 + o)) * 9216 + q0base + qb + qg;
    float4v r4 = *(const float4v*)&inl[oid];
    float4v y;
#pragma unroll
    for (int j = 0; j < 4; j++) y[j] = 0.25f * s[j] + r4[j];
    *(float4v*)&out[oid] = y;
  }
}

extern "C" void kernel_launch(void* const* d_in, const int* in_sizes, int n_in,
                              void* d_out, int out_size, void* d_ws, size_t ws_size,
                              hipStream_t stream)
{
  (void)in_sizes; (void)n_in; (void)out_size;
  const float* input_l = (const float*)d_in[0];
  const float* input_s = (const float*)d_in[1];
  const float* w_mlb = (const float*)d_in[2];
  const float* b_mlb = (const float*)d_in[3];
  const float* a_mlb = (const float*)d_in[4];
  const float* w_m   = (const float*)d_in[5];
  const float* b_m   = (const float*)d_in[6];
  const float* a_m   = (const float*)d_in[7];
  const float* w_asm = (const float*)d_in[8];
  const float* b_asm = (const float*)d_in[9];
  const float* a_asm = (const float*)d_in[10];
  float* out = (float*)d_out;

  char* base = (char*)d_ws;
  size_t off = 0;
  auto carve = [&](size_t bytes) -> char* {
    char* r = base + off;
    off += (bytes + 255) & ~(size_t)255;
    return r;
  };

  float* MBpad   = (float*)carve((size_t)4 * 32 * 98 * 98 * 4);
  float* REFpad  = (float*)carve((size_t)4 * 32 * 50 * 50 * 4);
  float* BASEpad = (float*)carve((size_t)4 * 64 * 50 * 50 * 4);
  bf16*  Kp      = (bf16*)carve((size_t)4 * 2304 * 288 * 2);
  bf16*  Xp      = (bf16*)carve((size_t)4 * 9216 * 288 * 2);
  bf16*  Bb      = (bf16*)carve((size_t)4 * 64 * 2304 * 2);
  float* statsM  = (float*)carve((size_t)9 * 9216 * 4);
  float* statsZ  = (float*)carve((size_t)9 * 9216 * 4);
  float* alpha   = (float*)carve((size_t)9 * 9216 * 4);
  size_t fixedOff = off;

  auto need = [&](int qmax, int psplit) -> size_t {
    size_t a = ((size_t)qmax * 2304 * 2 + 255) & ~(size_t)255;
    size_t b2 = ((size_t)psplit * 2304 * 2 + 255) & ~(size_t)255;
    return fixedOff + a + b2;
  };
  int nsplit, qmax, psplit;
  if (need(9216, 9216) <= ws_size)      { nsplit = 1; qmax = 9216; psplit = 9216; }
  else if (need(5120, 4608) <= ws_size) { nsplit = 2; qmax = 5120; psplit = 4608; }
  else                                  { nsplit = 4; qmax = 2816; psplit = 2304; }

  bf16* attnT = (bf16*)carve((size_t)qmax * 2304 * 2);
  bf16* A2    = (bf16*)carve((size_t)psplit * 2304 * 2);

  // ---- prep (all samples) ----
  {
    int t1 = 4 * 32 * 98 * 98;
    k_conv1x1<<<dim3((t1 + 255) / 256), dim3(256), 0, stream>>>(input_l, w_mlb, b_mlb, a_mlb, MBpad, 32, 96, 96, t1);
    int t2 = 4 * 32 * 50 * 50;
    k_conv1x1<<<dim3((t2 + 255) / 256), dim3(256), 0, stream>>>(input_s, w_m, b_m, a_m, REFpad, 32, 48, 48, t2);
    int t3 = 4 * 64 * 50 * 50;
    k_conv1x1<<<dim3((t3 + 255) / 256), dim3(256), 0, stream>>>(input_s, w_asm, b_asm, a_asm, BASEpad, 64, 48, 48, t3);
    k_kp<<<dim3(2304), dim3(256), 0, stream>>>(REFpad, Kp);
    int t4 = 4 * 9216 * 288;
    k_xp<<<dim3(t4 / 256), dim3(256), 0, stream>>>(MBpad, Xp, t4);
    int t5 = 4 * 64 * 2304;
    k_baseT<<<dim3(t5 / 256), dim3(256), 0, stream>>>(BASEpad, Bb, t5);
  }

  // ---- attention per (sample, query band) ----
  for (int n = 0; n < 4; n++) {
    for (int s = 0; s < nsplit; s++) {
      int q0 = s * psplit;
      int qlo = q0 - 256; if (qlo < 0) qlo = 0;
      int qhi = q0 + psplit + 256; if (qhi > 9216) qhi = 9216;
      int qlen = qhi - qlo;  // multiple of 256 by construction
      k_qk<<<dim3(qlen / 64, 9), dim3(256), 0, stream>>>(Xp, Kp, attnT, statsM, statsZ, n, qlo);
      k_alpha<<<dim3(qlen / 256), dim3(256), 0, stream>>>(statsM, statsZ, alpha, qlo, qlen);
      k_a2<<<dim3(psplit * 288 / 256), dim3(256), 0, stream>>>(attnT, alpha, A2, q0, qlo);
      k_pv3<<<dim3(psplit / 16), dim3(256), 0, stream>>>(A2, Bb, input_l, out, n, q0);
    }
  }
}

// Round 7
// 597.345 us; speedup vs baseline: 1.6118x; 1.0353x over previous
//
#include <hip/hip_runtime.h>
#include <hip/hip_bf16.h>
#include <cstdint>
#include <cstddef>

typedef __hip_bfloat16 bf16;
using short8 = __attribute__((ext_vector_type(8))) short;
using f32x4  = __attribute__((ext_vector_type(4))) float;
using float4v = __attribute__((ext_vector_type(4))) float;
using uint4v  = __attribute__((ext_vector_type(4))) unsigned int;

__device__ __forceinline__ float s2f(short s) {
  unsigned u = ((unsigned)(unsigned short)s) << 16;
  return __builtin_bit_cast(float, u);
}
__device__ __forceinline__ short f2s(float f) {  // RNE f32->bf16
  unsigned u = __builtin_bit_cast(unsigned, f);
  u += 0x7fffu + ((u >> 16) & 1u);
  return (short)(u >> 16);
}
__device__ __forceinline__ float bclo(unsigned u) { return __builtin_bit_cast(float, u << 16); }
__device__ __forceinline__ float bchi(unsigned u) { return __builtin_bit_cast(float, u & 0xFFFF0000u); }

// ---------------- merged 1x1 conv + PReLU into zero-padded (+1 ring) f32 outputs ----
__global__ __launch_bounds__(256) void k_conv_all(
    const float* __restrict__ in_l, const float* __restrict__ in_s,
    const float* __restrict__ w_mlb, const float* __restrict__ b_mlb, const float* __restrict__ a_mlb,
    const float* __restrict__ w_m,   const float* __restrict__ b_m,   const float* __restrict__ a_m,
    const float* __restrict__ w_asm, const float* __restrict__ b_asm, const float* __restrict__ a_asm,
    float* __restrict__ MBpad, float* __restrict__ REFpad, float* __restrict__ BASEpad,
    int t1, int t2, int t3)
{
  int idx = blockIdx.x * 256 + threadIdx.x;
  const float *in, *w, *bi, *ap; float* o; int Cout, Hin, Win;
  if (idx < t1) { in = in_l; w = w_mlb; bi = b_mlb; ap = a_mlb; o = MBpad; Cout = 32; Hin = 96; Win = 96; }
  else if (idx < t1 + t2) { idx -= t1; in = in_s; w = w_m; bi = b_m; ap = a_m; o = REFpad; Cout = 32; Hin = 48; Win = 48; }
  else if (idx < t1 + t2 + t3) { idx -= t1 + t2; in = in_s; w = w_asm; bi = b_asm; ap = a_asm; o = BASEpad; Cout = 64; Hin = 48; Win = 48; }
  else return;
  int Wp = Win + 2, Hp = Hin + 2;
  int x = idx % Wp;
  int t = idx / Wp;
  int y = t % Hp; t /= Hp;
  int oc = t % Cout; int n = t / Cout;
  if (x == 0 || x == Wp - 1 || y == 0 || y == Hp - 1) { o[idx] = 0.0f; return; }
  int cs = Hin * Win;
  const float* ip = in + (size_t)n * 64 * cs + (size_t)(y - 1) * Win + (x - 1);
  const float* wp = w + oc * 64;
  float s = bi[oc];
#pragma unroll 16
  for (int ci = 0; ci < 64; ci++)
    s += wp[ci] * ip[(size_t)ci * cs];
  float a = ap[0];
  o[idx] = s >= 0.0f ? s : a * s;
}

// ---------------- merged gather/pack: Kp (stride 320) + Xp (stride 320) + Bb --------
__global__ __launch_bounds__(256) void k_gather_all(
    const float* __restrict__ mbpad, const float* __restrict__ refpad,
    const float* __restrict__ basepad,
    bf16* __restrict__ Kp, bf16* __restrict__ Xp, bf16* __restrict__ Bb)
{
  int b = blockIdx.x;
  int tid = threadIdx.x;
  if (b < 2304) {
    // key patches, L2-normalized, scale 10 folded; one wave per (n,l); stride 320
    int wid = b * 4 + (tid >> 6);
    int lane = tid & 63;
    int n = wid / 2304, l = wid % 2304, lh = l / 48, lw = l % 48;
    float v[5]; float ss = 0.f;
#pragma unroll
    for (int i = 0; i < 5; i++) {
      int k = lane + 64 * i; v[i] = 0.f;
      if (k < 288) {
        int c = k / 9, rr = (k % 9) / 3, sc = k % 3;
        v[i] = refpad[((size_t)(n * 32 + c) * 50 + lh + rr) * 50 + lw + sc];
        ss += v[i] * v[i];
      }
    }
#pragma unroll
    for (int off = 32; off; off >>= 1) ss += __shfl_xor(ss, off);
    float inv = 10.f / (sqrtf(ss) + 1e-4f);
#pragma unroll
    for (int i = 0; i < 5; i++) {
      int k = lane + 64 * i;
      Kp[(size_t)wid * 320 + k] = __float2bfloat16(k < 288 ? v[i] * inv : 0.f);
    }
  } else if (b < 2304 + 46080) {
    // query patches Xp[n][p][320]
    int idx = (b - 2304) * 256 + tid;
    int k = idx % 320; int p = (idx / 320) % 9216; int n = idx / (320 * 9216);
    float val = 0.f;
    if (k < 288) {
      int c = k / 9, rr = (k % 9) / 3, sc = k % 3;
      int ph = p / 96, pw = p % 96;
      val = mbpad[((size_t)(n * 32 + c) * 98 + ph + rr) * 98 + pw + sc];
    }
    Xp[idx] = __float2bfloat16(val);
  } else {
    // base value matrix Bb[n][o][l]
    int idx = (b - 48384) * 256 + tid;
    int l = idx % 2304; int o = (idx / 2304) % 64; int n = idx / (2304 * 64);
    int lh = l / 48, lw = l % 48;
    Bb[idx] = __float2bfloat16(basepad[((size_t)(n * 64 + o) * 50 + lh + 1) * 50 + lw + 1]);
  }
}

// ---------------- stage 1: QK tile GEMM + chunk-local softmax, writes P~ ------------
// block: 64q x 256l, 2x2 waves of 32q x 128l. 64-wide k-stages, register prefetch
// of next stage's Ks (latency overlap), +8-pad LDS (no swizzle), 10 barriers total.
__global__ __launch_bounds__(256, 3) void k_qk(
    const bf16* __restrict__ Xp, const bf16* __restrict__ Kp,
    bf16* __restrict__ attnT, float* __restrict__ statsM, float* __restrict__ statsZ,
    int n, int qlo)
{
  __shared__ __align__(16) short KsPs[256 * 72];   // union: Ks 256x(64+8) / Ps 64x264
  __shared__ float Sm[2][2][32];
  __shared__ float Sz[2][2][32];
  int tid = threadIdx.x, lane = tid & 63, wv = tid >> 6;
  int quad = lane >> 4, m16 = lane & 15;
  int wr = wv >> 1, wc = wv & 1;
  int q0 = qlo + blockIdx.x * 64;
  int l0 = blockIdx.y * 256;

  f32x4 acc[2][8];
#pragma unroll
  for (int mi = 0; mi < 2; mi++)
#pragma unroll
    for (int t = 0; t < 8; t++) acc[mi][t] = (f32x4){0.f, 0.f, 0.f, 0.f};

  const short* Xrow = (const short*)Xp + ((size_t)n * 9216 + q0 + wr * 32 + m16) * 320;
  const short* Ksrc = (const short*)Kp + ((size_t)n * 2304 + l0) * 320;
  int srow = tid >> 2;            // 0..63 (rows srow + 64p)
  int scol = (tid & 3) * 16;      // 0,16,32,48

  short8 pf[8];
#pragma unroll
  for (int p = 0; p < 4; p++)
#pragma unroll
    for (int v = 0; v < 2; v++)
      pf[p * 2 + v] = *(const short8*)&Ksrc[(size_t)(srow + 64 * p) * 320 + scol + v * 8];

#pragma unroll
  for (int s = 0; s < 5; s++) {
    if (s) __syncthreads();
#pragma unroll
    for (int p = 0; p < 4; p++)
#pragma unroll
      for (int v = 0; v < 2; v++)
        *(short8*)&KsPs[(srow + 64 * p) * 72 + scol + v * 8] = pf[p * 2 + v];
    if (s < 4) {
#pragma unroll
      for (int p = 0; p < 4; p++)
#pragma unroll
        for (int v = 0; v < 2; v++)
          pf[p * 2 + v] = *(const short8*)&Ksrc[(size_t)(srow + 64 * p) * 320 + (s + 1) * 64 + scol + v * 8];
    }
    __syncthreads();
#pragma unroll
    for (int half = 0; half < 2; half++) {
      int kc = s * 64 + half * 32;
      if (kc >= 288) break;       // K=288; skip zero tail
      short8 a0 = *(const short8*)&Xrow[kc + quad * 8];
      short8 a1 = *(const short8*)&Xrow[16 * 320 + kc + quad * 8];
#pragma unroll
      for (int t = 0; t < 8; t++) {
        short8 bfr = *(const short8*)&KsPs[(wc * 128 + t * 16 + m16) * 72 + half * 32 + quad * 8];
        acc[0][t] = __builtin_amdgcn_mfma_f32_16x16x32_bf16(a0, bfr, acc[0][t], 0, 0, 0);
        acc[1][t] = __builtin_amdgcn_mfma_f32_16x16x32_bf16(a1, bfr, acc[1][t], 0, 0, 0);
      }
    }
  }

  // local stats over this wave's 128 l
  float mloc[2][4], zloc[2][4], scale[2][4];
#pragma unroll
  for (int mi = 0; mi < 2; mi++)
#pragma unroll
    for (int r = 0; r < 4; r++) mloc[mi][r] = -3.0e38f;
#pragma unroll
  for (int mi = 0; mi < 2; mi++)
#pragma unroll
    for (int t = 0; t < 8; t++)
#pragma unroll
      for (int r = 0; r < 4; r++) mloc[mi][r] = fmaxf(mloc[mi][r], acc[mi][t][r]);
#pragma unroll
  for (int off = 1; off < 16; off <<= 1)
#pragma unroll
    for (int mi = 0; mi < 2; mi++)
#pragma unroll
      for (int r = 0; r < 4; r++) mloc[mi][r] = fmaxf(mloc[mi][r], __shfl_xor(mloc[mi][r], off));
#pragma unroll
  for (int mi = 0; mi < 2; mi++)
#pragma unroll
    for (int r = 0; r < 4; r++) zloc[mi][r] = 0.f;
#pragma unroll
  for (int mi = 0; mi < 2; mi++)
#pragma unroll
    for (int t = 0; t < 8; t++)
#pragma unroll
      for (int r = 0; r < 4; r++) {
        float e = __expf(acc[mi][t][r] - mloc[mi][r]);
        acc[mi][t][r] = e;
        zloc[mi][r] += e;
      }
#pragma unroll
  for (int off = 1; off < 16; off <<= 1)
#pragma unroll
    for (int mi = 0; mi < 2; mi++)
#pragma unroll
      for (int r = 0; r < 4; r++) zloc[mi][r] += __shfl_xor(zloc[mi][r], off);
  if (m16 == 0) {
#pragma unroll
    for (int mi = 0; mi < 2; mi++)
#pragma unroll
      for (int r = 0; r < 4; r++) {
        int qi = mi * 16 + quad * 4 + r;
        Sm[wc][wr][qi] = mloc[mi][r];
        Sz[wc][wr][qi] = zloc[mi][r];
      }
  }
  __syncthreads();   // stats visible; also guards Ks reuse as Ps below
#pragma unroll
  for (int mi = 0; mi < 2; mi++)
#pragma unroll
    for (int r = 0; r < 4; r++) {
      int qi = mi * 16 + quad * 4 + r;
      float mo = Sm[wc ^ 1][wr][qi];
      float zo = Sz[wc ^ 1][wr][qi];
      float mc = fmaxf(mloc[mi][r], mo);
      float sc = __expf(mloc[mi][r] - mc);
      scale[mi][r] = sc;
      if (m16 == 0 && wc == 0) {
        float zc = zloc[mi][r] * sc + zo * __expf(mo - mc);
        int qq = q0 + wr * 32 + qi;
        statsM[blockIdx.y * 9216 + qq] = mc;
        statsZ[blockIdx.y * 9216 + qq] = zc;
      }
    }
  // write P~ tile through LDS (coalesced global stores)
#pragma unroll
  for (int mi = 0; mi < 2; mi++)
#pragma unroll
    for (int t = 0; t < 8; t++)
#pragma unroll
      for (int r = 0; r < 4; r++)
        KsPs[(wr * 32 + mi * 16 + quad * 4 + r) * 264 + wc * 128 + t * 16 + m16] =
            f2s(acc[mi][t][r] * scale[mi][r]);
  __syncthreads();
  {
    int row = tid >> 2, part = tid & 3;
    short* dst = (short*)attnT + (size_t)(q0 - qlo + row) * 2304 + l0 + part * 64;
    const short* sp = &KsPs[row * 264 + part * 64];
#pragma unroll
    for (int v = 0; v < 8; v++)
      *(short8*)&dst[v * 8] = *(const short8*)&sp[v * 8];
  }
}

// ---------------- stage 2: combine chunk stats -> alpha[c][q] ----------------
__global__ __launch_bounds__(256) void k_alpha(
    const float* __restrict__ statsM, const float* __restrict__ statsZ,
    float* __restrict__ alpha, int qlo, int qlen)
{
  int i = blockIdx.x * 256 + threadIdx.x;
  if (i >= qlen) return;
  int q = qlo + i;
  float M = -3.0e38f;
#pragma unroll
  for (int c = 0; c < 9; c++) M = fmaxf(M, statsM[c * 9216 + q]);
  float Z = 0.f;
#pragma unroll
  for (int c = 0; c < 9; c++) Z += statsZ[c * 9216 + q] * __expf(statsM[c * 9216 + q] - M);
  float invZ = 1.f / Z;
#pragma unroll
  for (int c = 0; c < 9; c++) alpha[c * 9216 + q] = __expf(statsM[c * 9216 + q] - M) * invZ;
}

// ---- stage 3: 9-point diagonal stencil with fused alpha, 16 l per thread ----------
// A2[l,q] = sum_d P~[l+dl, q+dq] * alpha[c(l+dl)][q+dq]
// aligned uint4 loads + funnel shifts; XCD-swizzled contiguous q bands.
__global__ __launch_bounds__(256) void k_a2(
    const bf16* __restrict__ attnT, const float* __restrict__ alpha,
    bf16* __restrict__ A2, int q0, int qlo)
{
  int bpx = gridDim.x >> 3;
  int nb = (blockIdx.x & 7) * bpx + (blockIdx.x >> 3);
  int g = nb * 256 + threadIdx.x;
  int qrel = g / 144;                 // 144 groups of 16 per q row
  int j = g - qrel * 144;
  int l0 = j * 16;
  int q = q0 + qrel;
  int h = q / 96, w = q - h * 96;
  int lh = l0 / 48, lw0 = l0 - lh * 48;   // 0,16,32 (16 | 48: never crosses lh rows)
  const short* att = (const short*)attnT;
  float acc[16];
#pragma unroll
  for (int k = 0; k < 16; k++) acc[k] = 0.f;
#pragma unroll
  for (int di = -1; di <= 1; di++) {
    int hh = h + di, lhh = lh + di;
    if (hh < 0 || hh >= 96 || lhh < 0 || lhh >= 48) continue;
    int lb = l0 + 48 * di;            // multiple of 16 -> 32B aligned
    int qv = q + 96 * di;
    const short* r0 = att + (size_t)(qv - qlo) * 2304;
    int c0 = lb >> 8;                 // 16-span never crosses a 256-chunk
    const float* alc = alpha + c0 * 9216;
    { // dj = 0
      float a = alc[qv];
      uint4v Va = *(const uint4v*)(r0 + lb);
      uint4v Vb = *(const uint4v*)(r0 + lb + 8);
#pragma unroll
      for (int k = 0; k < 4; k++) {
        acc[2 * k]      += bclo(Va[k]) * a;  acc[2 * k + 1]  += bchi(Va[k]) * a;
        acc[8 + 2 * k]  += bclo(Vb[k]) * a;  acc[9 + 2 * k]  += bchi(Vb[k]) * a;
      }
    }
    if (w > 0) { // dj = -1: shorts [lb-1 .. lb+14]; elem0 may be chunk c0-1
      const short* rm = r0 - 2304;
      int qp = qv - 1;
      float am = alc[qp];
      float a0 = ((lb & 255) == 0 && c0 > 0) ? alpha[(c0 - 1) * 9216 + qp] : am;
      uint4v Ma = *(const uint4v*)(rm + lb);
      uint4v Mb = *(const uint4v*)(rm + lb + 8);
      unsigned P = *(const unsigned*)(rm + lb - 2);
      unsigned D[8] = { Ma[0], Ma[1], Ma[2], Ma[3], Mb[0], Mb[1], Mb[2], Mb[3] };
      unsigned E0 = (P >> 16) | (D[0] << 16);
      if (lw0 == 0) E0 &= 0xFFFF0000u;     // elem0 would wrap to prev lh row
      acc[0] += bclo(E0) * a0;  acc[1] += bchi(E0) * am;
#pragma unroll
      for (int k = 1; k < 8; k++) {
        unsigned Ek = (D[k - 1] >> 16) | (D[k] << 16);
        acc[2 * k] += bclo(Ek) * am;  acc[2 * k + 1] += bchi(Ek) * am;
      }
    }
    if (w < 95) { // dj = +1: shorts [lb+1 .. lb+16]; elem15 may be chunk c0+1
      const short* rp = r0 + 2304;
      int qp = qv + 1;
      float am = alc[qp];
      float a15 = ((lb & 255) == 240 && c0 < 8) ? alpha[(c0 + 1) * 9216 + qp] : am;
      uint4v Pa = *(const uint4v*)(rp + lb);
      uint4v Pb = *(const uint4v*)(rp + lb + 8);
      unsigned N = *(const unsigned*)(rp + lb + 16);
      unsigned D[9] = { Pa[0], Pa[1], Pa[2], Pa[3], Pb[0], Pb[1], Pb[2], Pb[3], N };
      unsigned F7 = (D[7] >> 16) | (D[8] << 16);
      if (lw0 == 32) F7 &= 0x0000FFFFu;    // elem15 would wrap to next lh row
#pragma unroll
      for (int k = 0; k < 7; k++) {
        unsigned Fk = (D[k] >> 16) | (D[k + 1] << 16);
        acc[2 * k] += bclo(Fk) * am;  acc[2 * k + 1] += bchi(Fk) * am;
      }
      acc[14] += bclo(F7) * am;  acc[15] += bchi(F7) * a15;
    }
  }
  short8 o0, o1;
#pragma unroll
  for (int k = 0; k < 8; k++) { o0[k] = f2s(acc[k]); o1[k] = f2s(acc[8 + k]); }
  short* dst = (short*)A2 + (size_t)qrel * 2304 + l0;
  *(short8*)dst = o0;
  *(short8*)(dst + 8) = o1;
}

// ---- stage 4: PV GEMM, in-block split-K ------------------------------------------
// block = 16q x 64o; 4 waves each own 576 of K=2304 (no barriers in k-loop),
// LDS reduction, fused 0.25*C + residual epilogue. A2 streamed exactly once.
__global__ __launch_bounds__(256) void k_pv3(
    const bf16* __restrict__ A2, const bf16* __restrict__ Bb,
    const float* __restrict__ inl, float* __restrict__ out,
    int n, int q0base)
{
  __shared__ float Cred[4][16][67];
  int tid = threadIdx.x, lane = tid & 63, wv = tid >> 6;
  int quad = lane >> 4, m16 = lane & 15;
  int qb = blockIdx.x * 16;
  int kbase = wv * 576;
  f32x4 acc[4];
#pragma unroll
  for (int t = 0; t < 4; t++) acc[t] = (f32x4){0.f, 0.f, 0.f, 0.f};

  const short* Ap = (const short*)A2 + (size_t)qb * 2304 + kbase;
  const short* Bp = (const short*)Bb + (size_t)n * 64 * 2304 + kbase;

#pragma unroll
  for (int it = 0; it < 9; it++) {
    int kw = it * 64;
#pragma unroll
    for (int ks = 0; ks < 64; ks += 32) {
      short8 a = *(const short8*)&Ap[(size_t)m16 * 2304 + kw + ks + quad * 8];
#pragma unroll
      for (int ni = 0; ni < 4; ni++) {
        short8 b = *(const short8*)&Bp[(size_t)(ni * 16 + m16) * 2304 + kw + ks + quad * 8];
        acc[ni] = __builtin_amdgcn_mfma_f32_16x16x32_bf16(a, b, acc[ni], 0, 0, 0);
      }
    }
  }
#pragma unroll
  for (int ni = 0; ni < 4; ni++)
#pragma unroll
    for (int r = 0; r < 4; r++)
      Cred[wv][quad * 4 + r][ni * 16 + m16] = acc[ni][r];
  __syncthreads();
  {
    int o = tid >> 2;                // 0..63
    int qg = (tid & 3) * 4;          // 0..12
    float4v s;
#pragma unroll
    for (int j = 0; j < 4; j++)
      s[j] = Cred[0][qg + j][o] + Cred[1][qg + j][o] + Cred[2][qg + j][o] + Cred[3][qg + j][o];
    size_t oid = ((size_t)(n * 64 + o)) * 9216 + q0base + qb + qg;
    float4v r4 = *(const float4v*)&inl[oid];
    float4v y;
#pragma unroll
    for (int j = 0; j < 4; j++) y[j] = 0.25f * s[j] + r4[j];
    *(float4v*)&out[oid] = y;
  }
}

extern "C" void kernel_launch(void* const* d_in, const int* in_sizes, int n_in,
                              void* d_out, int out_size, void* d_ws, size_t ws_size,
                              hipStream_t stream)
{
  (void)in_sizes; (void)n_in; (void)out_size;
  const float* input_l = (const float*)d_in[0];
  const float* input_s = (const float*)d_in[1];
  const float* w_mlb = (const float*)d_in[2];
  const float* b_mlb = (const float*)d_in[3];
  const float* a_mlb = (const float*)d_in[4];
  const float* w_m   = (const float*)d_in[5];
  const float* b_m   = (const float*)d_in[6];
  const float* a_m   = (const float*)d_in[7];
  const float* w_asm = (const float*)d_in[8];
  const float* b_asm = (const float*)d_in[9];
  const float* a_asm = (const float*)d_in[10];
  float* out = (float*)d_out;

  char* base = (char*)d_ws;
  size_t off = 0;
  auto carve = [&](size_t bytes) -> char* {
    char* r = base + off;
    off += (bytes + 255) & ~(size_t)255;
    return r;
  };

  float* MBpad   = (float*)carve((size_t)4 * 32 * 98 * 98 * 4);
  float* REFpad  = (float*)carve((size_t)4 * 32 * 50 * 50 * 4);
  float* BASEpad = (float*)carve((size_t)4 * 64 * 50 * 50 * 4);
  bf16*  Kp      = (bf16*)carve((size_t)4 * 2304 * 320 * 2);
  bf16*  Xp      = (bf16*)carve((size_t)4 * 9216 * 320 * 2);
  bf16*  Bb      = (bf16*)carve((size_t)4 * 64 * 2304 * 2);
  float* statsM  = (float*)carve((size_t)9 * 9216 * 4);
  float* statsZ  = (float*)carve((size_t)9 * 9216 * 4);
  float* alpha   = (float*)carve((size_t)9 * 9216 * 4);
  size_t fixedOff = off;

  auto need = [&](int qmax, int psplit) -> size_t {
    size_t a = ((size_t)qmax * 2304 * 2 + 255) & ~(size_t)255;
    size_t b2 = ((size_t)psplit * 2304 * 2 + 255) & ~(size_t)255;
    return fixedOff + a + b2;
  };
  int nsplit, qmax, psplit;
  if (need(9216, 9216) <= ws_size)      { nsplit = 1; qmax = 9216; psplit = 9216; }
  else if (need(5120, 4608) <= ws_size) { nsplit = 2; qmax = 5120; psplit = 4608; }
  else                                  { nsplit = 4; qmax = 2816; psplit = 2304; }

  bf16* attnT = (bf16*)carve((size_t)qmax * 2304 * 2);
  bf16* A2    = (bf16*)carve((size_t)psplit * 2304 * 2);

  // ---- prep (all samples, 2 dispatches) ----
  {
    int t1 = 4 * 32 * 98 * 98;
    int t2 = 4 * 32 * 50 * 50;
    int t3 = 4 * 64 * 50 * 50;
    int tt = t1 + t2 + t3;
    k_conv_all<<<dim3((tt + 255) / 256), dim3(256), 0, stream>>>(
        input_l, input_s, w_mlb, b_mlb, a_mlb, w_m, b_m, a_m, w_asm, b_asm, a_asm,
        MBpad, REFpad, BASEpad, t1, t2, t3);
    k_gather_all<<<dim3(2304 + 46080 + 2304), dim3(256), 0, stream>>>(
        MBpad, REFpad, BASEpad, Kp, Xp, Bb);
  }

  // ---- attention per (sample, query band) ----
  for (int n = 0; n < 4; n++) {
    for (int s = 0; s < nsplit; s++) {
      int q0 = s * psplit;
      int qlo = q0 - 256; if (qlo < 0) qlo = 0;
      int qhi = q0 + psplit + 256; if (qhi > 9216) qhi = 9216;
      int qlen = qhi - qlo;  // multiple of 256 by construction
      k_qk<<<dim3(qlen / 64, 9), dim3(256), 0, stream>>>(Xp, Kp, attnT, statsM, statsZ, n, qlo);
      k_alpha<<<dim3(qlen / 256), dim3(256), 0, stream>>>(statsM, statsZ, alpha, qlo, qlen);
      k_a2<<<dim3(psplit * 144 / 256), dim3(256), 0, stream>>>(attnT, alpha, A2, q0, qlo);
      k_pv3<<<dim3(psplit / 16), dim3(256), 0, stream>>>(A2, Bb, input_l, out, n, q0);
    }
  }
}